// Round 9
// baseline (130.359 us; speedup 1.0000x reference)
//
#include <hip/hip_runtime.h>
#include <hip/hip_cooperative_groups.h>

namespace cg = cooperative_groups;

// ST-GCN fused block for MI355X (gfx950).  FP32 I/O, bf16 at MFMA boundaries.
// Preferred: ONE cooperative dispatch (1024 blocks = 256 CU x 4):
//   phase A: window-sum (each block: 8 l's x 32 ci, tile aliases T1) + prep
//            distributed over five n==1 blocks -> xs/tables/statsbuf
//   grid.sync (fences publish xs/tables/zeros)
//   phase B: stage1/stage2 MFMA (B-frags direct from xs), z -> regs
//   phase C: zl park (T1 alias) -> stats atomics -> x prefetch -> grid.sync
//            -> per-block 16 KB stats reduce -> BN+ReLU+residual f32x4 out.
// Fallback: kwin -> kmain<false> -> zb -> kapply (verified 3-dispatch path).
// xs layout: [n][l][25 v][64 ci] bf16.   statsbuf: 32 copies x 128 f32.

typedef unsigned short ushort_t;
typedef __attribute__((ext_vector_type(8))) short short8;   // 8 x bf16 MFMA frag
typedef __attribute__((ext_vector_type(4))) float f32x4;
typedef __attribute__((ext_vector_type(4))) unsigned short us4;

#define N_  4
#define CI_ 64
#define CO_ 64
#define L_  1024
#define V_  25
#define P_  3
#define KS_ 9
#define NLV 102400.0f   // N_*L_*V_  (BN population count per channel)
#define NREP 32         // stats replication factor
#define TSTR 406        // window tile row stride (ushort); u32-friendly

__device__ __forceinline__ float b2f(ushort_t u) {
  union { float f; unsigned int i; } c; c.i = ((unsigned int)u) << 16; return c.f;
}
__device__ __forceinline__ ushort_t f2b(float f) {
  union { float f; unsigned int i; } c; c.f = f;
  unsigned int u = c.i;
  u += 0x7fffu + ((u >> 16) & 1u);      // round-to-nearest-even
  return (ushort_t)(u >> 16);
}

// ---------------------------------------------------------------------------
// kwin (FALLBACK only): window-sum + prep, as verified in R8.
__global__ __launch_bounds__(256) void kwin(
    const float* __restrict__ x, ushort_t* __restrict__ xs,
    const float* __restrict__ A, const float* __restrict__ E,
    const float* __restrict__ cb, const float* __restrict__ W,
    ushort_t* __restrict__ a2raw, float* __restrict__ biastab,
    ushort_t* __restrict__ wb, float* __restrict__ statsbuf)
{
  const int bx = blockIdx.x;                    // 0..256
  const int n = blockIdx.y;
  const int tid = threadIdx.x;

  if (bx == 256) {                              // ---- prep block ----
    if (n != 0) return;
    __shared__ float colA[P_ * 32];
    if (tid < P_ * 32) {
      int p = tid >> 5, w = tid & 31;
      float s = 0.f;
      if (w < V_)
        for (int v = 0; v < V_; ++v) {
          int idx = (p * V_ + v) * V_ + w;
          s += A[idx] * E[idx];
        }
      colA[tid] = s;
    }
    for (int e = tid; e < 32 * 96; e += 256) {
      int w = e / 96, k = e - w * 96;
      int p = k >> 5, v = k & 31;
      float val = 0.f;
      if (w < V_ && v < V_) {
        int idx = (p * V_ + v) * V_ + w;
        val = A[idx] * E[idx];
      }
      a2raw[e] = f2b(val);
    }
    for (int e = tid; e < 192 * 64; e += 256) wb[e] = f2b(W[e]);
    __syncthreads();
    for (int e = tid; e < 32 * 64; e += 256) {
      int w = e >> 6, c = e & 63;
      float s = 0.f;
      for (int p = 0; p < P_; ++p) s += cb[p * 64 + c] * colA[p * 32 + w];
      biastab[e] = s;
    }
    for (int e = tid; e < NREP * 128; e += 256) statsbuf[e] = 0.f;
    return;
  }

  const int chunk = bx >> 1, half = bx & 1;     // 8 l's, 32 ci
  __shared__ __align__(16) ushort_t tile[32 * TSTR];
  const int l0 = chunk * 8;
  const long xn = (long)n * CI_ * L_ * V_ + (long)(half * 32) * (L_ * V_);
  for (int m = tid; m < 3200; m += 256) {
    int ci = m / 100;
    int j4 = (m - ci * 100) * 4;
    f32x4 d;
    if (chunk == 0 && j4 < 200) {
      d = (f32x4){0.f, 0.f, 0.f, 0.f};
    } else {
      d = *(const f32x4*)(x + xn + (long)ci * (L_ * V_) + (l0 - 8) * V_ + j4);
    }
    unsigned int p0 = (unsigned int)f2b(d[0]) | ((unsigned int)f2b(d[1]) << 16);
    unsigned int p1 = (unsigned int)f2b(d[2]) | ((unsigned int)f2b(d[3]) << 16);
    *(unsigned int*)(&tile[ci * TSTR + j4])     = p0;
    *(unsigned int*)(&tile[ci * TSTR + j4 + 2]) = p1;
  }
  __syncthreads();
  const long xsbase = ((long)n * L_ + l0) * 1600 + half * 32;
  for (int cp = tid; cp < 400; cp += 256) {
    const int v = cp >> 4, ci = (cp & 15) * 2;
    const ushort_t* c0 = &tile[ci * TSTR + v];
    const ushort_t* c1 = c0 + TSTR;
    float s0 = 0.f, s1 = 0.f;
#pragma unroll
    for (int li = 0; li < 9; ++li) { s0 += b2f(c0[li * 25]); s1 += b2f(c1[li * 25]); }
    *(unsigned int*)(xs + xsbase + v * 64 + ci) =
        (unsigned int)f2b(s0) | ((unsigned int)f2b(s1) << 16);
#pragma unroll
    for (int l_ = 1; l_ < 8; ++l_) {
      s0 += b2f(c0[(l_ + 8) * 25]) - b2f(c0[(l_ - 1) * 25]);
      s1 += b2f(c1[(l_ + 8) * 25]) - b2f(c1[(l_ - 1) * 25]);
      *(unsigned int*)(xs + xsbase + l_ * 1600 + v * 64 + ci) =
          (unsigned int)f2b(s0) | ((unsigned int)f2b(s1) << 16);
    }
  }
}

// ---------------------------------------------------------------------------
// kmain<COOP>: COOP=true does window phase A + grid.sync + stage1/2 + BN out.
//              COOP=false is the verified fallback (xs from kwin, z -> zb).
template<bool COOP>
__global__ __launch_bounds__(256, 4) void kmain(
    const float*    __restrict__ x,       // [n][ci][l][v] f32
    ushort_t*       __restrict__ xs,      // [n][l][1600] bf16
    const float*    __restrict__ A, const float* __restrict__ E,
    const float*    __restrict__ cb, const float* __restrict__ W,
    ushort_t*       __restrict__ wb,      // [192][64] bf16
    ushort_t*       __restrict__ a2,      // [32 w][96 k] bf16
    float*          __restrict__ biastab, // [32 w][64 c] f32
    ushort_t*       __restrict__ zb,
    float*          __restrict__ statsbuf,
    const float*    __restrict__ gamma,
    const float*    __restrict__ beta,
    float*          __restrict__ out)
{
  const int lb = blockIdx.x;            // 4 l's per block (0..255)
  const int n  = blockIdx.y;
  const int tid = threadIdx.x, lane = tid & 63, wv = tid >> 6;
  const int m16 = lane & 15, quad = lane >> 4;

  __shared__ __align__(16) ushort_t T1[13312];   // [l_][c][104]  26.6 KB
  __shared__ float colA[P_ * 32];                // prep scratch   0.4 KB
  // COOP aliases: phase A tile = T1 (32x406 = 12,992), phase C zl = T1
  // (100x68), part = f32 @ T1[8192], scsh = f32 @ T1[8704].

  if constexpr (COOP) {
    // ================= phase A: window-sum (kwin folded in) ================
    ushort_t* tile = T1;
    const int chunk = lb >> 1, half = lb & 1;   // 8 l's, 32 ci
    const int l0 = chunk * 8;
    const long xn = (long)n * CI_ * L_ * V_ + (long)(half * 32) * (L_ * V_);
    for (int m = tid; m < 3200; m += 256) {
      int ci = m / 100;
      int j4 = (m - ci * 100) * 4;
      f32x4 d;
      if (chunk == 0 && j4 < 200) {
        d = (f32x4){0.f, 0.f, 0.f, 0.f};        // l < 0 halo
      } else {
        d = *(const f32x4*)(x + xn + (long)ci * (L_ * V_) + (l0 - 8) * V_ + j4);
      }
      unsigned int p0 = (unsigned int)f2b(d[0]) | ((unsigned int)f2b(d[1]) << 16);
      unsigned int p1 = (unsigned int)f2b(d[2]) | ((unsigned int)f2b(d[3]) << 16);
      *(unsigned int*)(&tile[ci * TSTR + j4])     = p0;
      *(unsigned int*)(&tile[ci * TSTR + j4 + 2]) = p1;
    }
    // distributed prep (five n==1 blocks do light extra duty)
    if (n == 1) {
      if (lb == 0) {
        for (int e = tid; e < 32 * 96; e += 256) {
          int w = e / 96, k = e - w * 96;
          int p = k >> 5, v = k & 31;
          float val = 0.f;
          if (w < V_ && v < V_) {
            int idx = (p * V_ + v) * V_ + w;
            val = A[idx] * E[idx];
          }
          a2[e] = f2b(val);
        }
      } else if (lb == 1) {
        for (int e = tid; e < 6144; e += 256) wb[e] = f2b(W[e]);
      } else if (lb == 2) {
        for (int e = tid; e < 6144; e += 256) wb[6144 + e] = f2b(W[6144 + e]);
      } else if (lb == 3) {
        for (int e = tid; e < NREP * 128; e += 256) statsbuf[e] = 0.f;
      } else if (lb == 4) {
        if (tid < P_ * 32) {
          int p = tid >> 5, w = tid & 31;
          float s = 0.f;
          if (w < V_)
            for (int v = 0; v < V_; ++v) {
              int idx = (p * V_ + v) * V_ + w;
              s += A[idx] * E[idx];
            }
          colA[tid] = s;
        }
      }
    }
    __syncthreads();
    const long xsbase = ((long)n * L_ + l0) * 1600 + half * 32;
    for (int cp = tid; cp < 400; cp += 256) {
      const int v = cp >> 4, ci = (cp & 15) * 2;
      const ushort_t* c0 = &tile[ci * TSTR + v];
      const ushort_t* c1 = c0 + TSTR;
      float s0 = 0.f, s1 = 0.f;
#pragma unroll
      for (int li = 0; li < 9; ++li) { s0 += b2f(c0[li * 25]); s1 += b2f(c1[li * 25]); }
      *(unsigned int*)(xs + xsbase + v * 64 + ci) =
          (unsigned int)f2b(s0) | ((unsigned int)f2b(s1) << 16);
#pragma unroll
      for (int l_ = 1; l_ < 8; ++l_) {
        s0 += b2f(c0[(l_ + 8) * 25]) - b2f(c0[(l_ - 1) * 25]);
        s1 += b2f(c1[(l_ + 8) * 25]) - b2f(c1[(l_ - 1) * 25]);
        *(unsigned int*)(xs + xsbase + l_ * 1600 + v * 64 + ci) =
            (unsigned int)f2b(s0) | ((unsigned int)f2b(s1) << 16);
      }
    }
    if (n == 1 && lb == 4) {
      for (int e = tid; e < 32 * 64; e += 256) {
        int w = e >> 6, c = e & 63;
        float s = 0.f;
        for (int p = 0; p < P_; ++p) s += cb[p * 64 + c] * colA[p * 32 + w];
        biastab[e] = s;
      }
    }
    cg::this_grid().sync();             // publish xs / tables / statsbuf zeros
  }

  // ================= phase B: stage1 + stage2 MFMA =======================
  short8 af[3][2];
#pragma unroll
  for (int i = 0; i < 3; ++i) {
    const ushort_t* wrow = wb + ((wv * 3 + i) * 16 + m16) * 64 + quad * 8;
    af[i][0] = *(const short8*)(wrow);
    af[i][1] = *(const short8*)(wrow + 32);
  }

  const ushort_t* xsb = xs + ((long)n * L_ + 4 * lb) * 1600;
  const int cbase = wv * 16 + quad * 4;
  float s1[4] = {0.f, 0.f, 0.f, 0.f}, s2[4] = {0.f, 0.f, 0.f, 0.f};
  us4 zpack[2][2][2];                   // [pair][l_][nt] — COOP keeps z in regs

#pragma unroll
  for (int pair = 0; pair < 2; ++pair) {
    // ---- stage 1: B-frags direct from global xs (predicated zero v>=25) ----
    short8 bfr[4][2];
#pragma unroll
    for (int nt = 0; nt < 4; ++nt) {
      const int v = (nt & 1) * 16 + m16;
      const int l_ = pair * 2 + (nt >> 1);
#pragma unroll
      for (int ks = 0; ks < 2; ++ks) {
        short8 t = (short8){0, 0, 0, 0, 0, 0, 0, 0};
        if (v < V_)
          t = *(const short8*)(xsb + l_ * 1600 + v * 64 + ks * 32 + quad * 8);
        bfr[nt][ks] = t;
      }
    }

    f32x4 acc1[3][4];
#pragma unroll
    for (int i = 0; i < 3; ++i)
#pragma unroll
      for (int j = 0; j < 4; ++j) acc1[i][j] = (f32x4){0.f, 0.f, 0.f, 0.f};

#pragma unroll
    for (int i = 0; i < 3; ++i)
#pragma unroll
      for (int nt = 0; nt < 4; ++nt) {
        acc1[i][nt] = __builtin_amdgcn_mfma_f32_16x16x32_bf16(af[i][0], bfr[nt][0], acc1[i][nt], 0, 0, 0);
        acc1[i][nt] = __builtin_amdgcn_mfma_f32_16x16x32_bf16(af[i][1], bfr[nt][1], acc1[i][nt], 0, 0, 0);
      }

    __syncthreads();                    // tile (pair 0) / prior T1 reads done
    // repack t1 -> T1[l_][c][p*32+v]  (D: row = quad*4+r, col = m16)
#pragma unroll
    for (int i = 0; i < 3; ++i) {
      const int mt = wv * 3 + i;
#pragma unroll
      for (int nt = 0; nt < 4; ++nt) {
        const int l_ = nt >> 1;
        const int col = (nt & 1) * 16 + m16;
#pragma unroll
        for (int r = 0; r < 4; ++r) {
          int k = mt * 16 + quad * 4 + r;        // k = p*64 + c
          T1[l_ * 6656 + (k & 63) * 104 + (k >> 6) * 32 + col] = f2b(acc1[i][nt][r]);
        }
      }
    }
    __syncthreads();

    // ---- stage 2: 12 MFMA; a2 B-frags loaded per pair (global, L1-hot) ----
    short8 bfr2[2][3];
#pragma unroll
    for (int nt = 0; nt < 2; ++nt)
#pragma unroll
      for (int ks = 0; ks < 3; ++ks)
        bfr2[nt][ks] = *(const short8*)(a2 + (nt * 16 + m16) * 96 + ks * 32 + quad * 8);

    f32x4 acc2[2][2];
#pragma unroll
    for (int l_ = 0; l_ < 2; ++l_)
#pragma unroll
      for (int nt = 0; nt < 2; ++nt) acc2[l_][nt] = (f32x4){0.f, 0.f, 0.f, 0.f};

#pragma unroll
    for (int l_ = 0; l_ < 2; ++l_)
#pragma unroll
      for (int ks = 0; ks < 3; ++ks) {
        short8 afT = *(const short8*)(&T1[l_ * 6656 + (wv * 16 + m16) * 104 + ks * 32 + quad * 8]);
        acc2[l_][0] = __builtin_amdgcn_mfma_f32_16x16x32_bf16(afT, bfr2[0][ks], acc2[l_][0], 0, 0, 0);
        acc2[l_][1] = __builtin_amdgcn_mfma_f32_16x16x32_bf16(afT, bfr2[1][ks], acc2[l_][1], 0, 0, 0);
      }

    // epilogue: + cnt(l)*bias (float4); z -> regs (COOP) or zb (fallback)
#pragma unroll
    for (int l_ = 0; l_ < 2; ++l_) {
      const int l = 4 * lb + pair * 2 + l_;
      const float cnt = (float)(l + 1 < KS_ ? l + 1 : KS_);
#pragma unroll
      for (int nt = 0; nt < 2; ++nt) {
        const int w = nt * 16 + m16;
        if (w < V_) {
          f32x4 bias = *(const f32x4*)(biastab + w * 64 + cbase);
          us4 pack;
#pragma unroll
          for (int r = 0; r < 4; ++r) {
            pack[r] = f2b(acc2[l_][nt][r] + cnt * bias[r]);
            float zr = b2f(pack[r]);            // stats on the stored value
            s1[r] += zr; s2[r] += zr * zr;
          }
          if constexpr (COOP)
            zpack[pair][l_][nt] = pack;
          else
            *(us4*)(&zb[(((long)(n * L_ + l) * V_ + w) << 6) + cbase]) = pack;
        }
      }
    }
  }
  // in-quad reduction over m16 (lanes of a quad share channels cbase..cbase+3)
#pragma unroll
  for (int off = 1; off < 16; off <<= 1) {
#pragma unroll
    for (int r = 0; r < 4; ++r) {
      s1[r] += __shfl_xor(s1[r], off, 64);
      s2[r] += __shfl_xor(s2[r], off, 64);
    }
  }
  if (m16 == 0) {
    float* sb = statsbuf + ((n * 256 + lb) & (NREP - 1)) * 128;
#pragma unroll
    for (int r = 0; r < 4; ++r) {
      atomicAdd(&sb[cbase + r], s1[r]);
      atomicAdd(&sb[64 + cbase + r], s2[r]);
    }
  }

  if constexpr (COOP) {
    // ================= phase C: BN finalize + output =======================
    __syncthreads();                    // T1 MFMA reads done; re-alias as zl
    ushort_t* zl = T1;                  // [rr][c^e], 100 x 68
#pragma unroll
    for (int pair = 0; pair < 2; ++pair)
#pragma unroll
      for (int l_ = 0; l_ < 2; ++l_)
#pragma unroll
        for (int nt = 0; nt < 2; ++nt) {
          const int w = nt * 16 + m16;
          if (w < V_) {
            const int rr = (pair * 2 + l_) * 25 + w;
            const int e = ((rr >> 2) & 31) << 1;
            const us4 pk = zpack[pair][l_][nt];
            *(unsigned int*)(&zl[rr * 68 + (cbase ^ e)]) =
                (unsigned int)pk[0] | ((unsigned int)pk[1] << 16);
            *(unsigned int*)(&zl[rr * 68 + ((cbase + 2) ^ e)]) =
                (unsigned int)pk[2] | ((unsigned int)pk[3] << 16);
          }
        }

    // prefetch phase-3 residual x (hides HBM under sync+reduce)
    const long obase = (long)(n * 64) * (L_ * V_) + lb * 100;
    f32x4 xv[7];
#pragma unroll
    for (int i = 0; i < 7; ++i) {
      const int m = tid + i * 256;
      if (m < 1600) {
        const int c = m / 25, q = m - c * 25;
        xv[i] = *(const f32x4*)(x + obase + (long)c * (L_ * V_) + q * 4);
      }
    }

    cg::this_grid().sync();             // all stats atomics done grid-wide

    // every block reduces the 16 KB statsbuf (L3-hot)
    float* part = (float*)&T1[8192];
    float* scsh = (float*)&T1[8704];
    {
      const int slot = tid & 127, hf = tid >> 7;
      float a = 0.f;
      for (int k = hf; k < NREP; k += 2)
        a += __hip_atomic_load(&statsbuf[k * 128 + slot],
                               __ATOMIC_RELAXED, __HIP_MEMORY_SCOPE_AGENT);
      part[tid] = a;
    }
    __syncthreads();
    if (tid < 64) {
      const float inv = 1.0f / NLV;
      float s    = part[tid]      + part[128 + tid];
      float sq   = part[64 + tid] + part[192 + tid];
      float mean = s * inv;
      float var  = sq * inv - mean * mean;
      float rstd = rsqrtf(var + 1e-5f);
      float g = gamma[tid];
      scsh[tid]      = rstd * g;
      scsh[64 + tid] = beta[tid] - mean * rstd * g;
    }
    __syncthreads();

    // BN + ReLU + residual, coalesced f32x4 out
#pragma unroll
    for (int i = 0; i < 7; ++i) {
      const int m = tid + i * 256;
      if (m < 1600) {
        const int c = m / 25, q = m - c * 25, rr = q * 4;
        const int e = q << 1;           // ((rr>>2)&31)<<1, q<25
        const long xi = obase + (long)c * (L_ * V_) + rr;
        const float scc = scsh[c], shc = scsh[64 + c];
        f32x4 o;
#pragma unroll
        for (int j = 0; j < 4; ++j) {
          float z = b2f(zl[(rr + j) * 68 + (c ^ e)]);
          float y = fmaxf(z * scc + shc, 0.f);
          o[j] = fmaxf(y + xv[i][j], 0.f);
        }
        *(f32x4*)(out + xi) = o;
      }
    }
  }
}

// ---------------------------------------------------------------------------
// kapply (fallback only).
__global__ __launch_bounds__(256) void kapply(
    const ushort_t* __restrict__ zb, const float* __restrict__ x,
    const float* __restrict__ statsbuf,
    const float* __restrict__ gamma, const float* __restrict__ beta,
    float* __restrict__ out)
{
  const int n = blockIdx.y, chunk = blockIdx.x;   // 8 l's per block
  const int tid = threadIdx.x;
  __shared__ __align__(16) ushort_t zl[200 * 66];
  __shared__ f32x4 red[8][32];
  __shared__ float sc[64], sh[64];
  const long zbase = (long)((n * L_ + chunk * 8) * V_) * 64;
  for (int m = tid; m < 6400; m += 256) {
    const int row = m >> 5, c2 = (m & 31) * 2;
    const int cs = c2 ^ (((row >> 2) & 31) << 1);
    *(unsigned int*)(&zl[row * 66 + cs]) = ((const unsigned int*)(zb + zbase))[m];
  }
  {
    const int s4 = tid & 31, grp = tid >> 5;
    const f32x4* sb4 = (const f32x4*)statsbuf;
    f32x4 a = (f32x4){0.f, 0.f, 0.f, 0.f};
    for (int k = grp; k < NREP; k += 8) {
      f32x4 v = sb4[k * 32 + s4];
      a[0] += v[0]; a[1] += v[1]; a[2] += v[2]; a[3] += v[3];
    }
    red[grp][s4] = a;
  }
  __syncthreads();
  if (tid < 64) {
    const float inv = 1.0f / NLV;
    float s = 0.f, sq = 0.f;
#pragma unroll
    for (int g = 0; g < 8; ++g) {
      s  += red[g][tid >> 2][tid & 3];
      sq += red[g][16 + (tid >> 2)][tid & 3];
    }
    float mean = s * inv;
    float var  = sq * inv - mean * mean;
    float rstd = rsqrtf(var + 1e-5f);
    float g = gamma[tid];
    sc[tid] = rstd * g;
    sh[tid] = beta[tid] - mean * rstd * g;
  }
  __syncthreads();
  const long obase = ((long)(n * 64) * L_ + chunk * 8) * V_;
  for (int m = tid; m < 3200; m += 256) {
    int c = m / 50, q = m - c * 50, rr = q * 4;
    const int e = ((q & 31) << 1);
    long xi = obase + (long)c * (L_ * V_) + rr;
    f32x4 xv = *(const f32x4*)(x + xi);
    const float scc = sc[c], shc = sh[c];
    f32x4 o;
#pragma unroll
    for (int j = 0; j < 4; ++j) {
      float z = b2f(zl[(rr + j) * 66 + (c ^ e)]);
      float y = fmaxf(z * scc + shc, 0.f);
      o[j] = fmaxf(y + xv[j], 0.f);
    }
    *(f32x4*)(out + xi) = o;
  }
}

// ---------------------------------------------------------------------------
extern "C" void kernel_launch(void* const* d_in, const int* in_sizes, int n_in,
                              void* d_out, int out_size, void* d_ws, size_t ws_size,
                              hipStream_t stream)
{
  const float* x     = (const float*)d_in[0];
  const float* A     = (const float*)d_in[1];
  const float* E     = (const float*)d_in[2];
  const float* W     = (const float*)d_in[3];
  const float* cb    = (const float*)d_in[4];
  const float* gamma = (const float*)d_in[5];
  const float* beta  = (const float*)d_in[6];
  float* out = (float*)d_out;

  char* ws = (char*)d_ws;
  const size_t XS_OFF   = 0;                       // 13,107,200 B (bf16 xs)
  const size_t ZB_OFF   = 13107200;                // 13,107,200 B (bf16 zb, fallback)
  const size_t WB_OFF   = 26214400;                // 24,576 B (bf16 Wb)
  const size_t A2_OFF   = WB_OFF + 32768;          // 6,144 B
  const size_t BIAS_OFF = A2_OFF + 16384;          // 8,192 B
  const size_t STAT_OFF = BIAS_OFF + 16384;        // 16,384 B (32 x 128 f32)
  ushort_t* xs       = (ushort_t*)(ws + XS_OFF);
  ushort_t* zb       = (ushort_t*)(ws + ZB_OFF);
  ushort_t* wb       = (ushort_t*)(ws + WB_OFF);
  ushort_t* a2       = (ushort_t*)(ws + A2_OFF);
  float*    biastab  = (float*)(ws + BIAS_OFF);
  float*    statsbuf = (float*)(ws + STAT_OFF);

  // validate cooperative residency (host-side query; capture-safe)
  auto kcoop = kmain<true>;
  int maxb = 0;
  hipError_t qe = hipOccupancyMaxActiveBlocksPerMultiprocessor(&maxb, kcoop, 256, 0);
  bool coop = (qe == hipSuccess) && (maxb >= 4);

  if (coop) {
    void* args[] = {(void*)&x, &xs, (void*)&A, (void*)&E, (void*)&cb, (void*)&W,
                    &wb, &a2, &biastab, &zb, &statsbuf,
                    (void*)&gamma, (void*)&beta, &out};
    hipError_t le = hipLaunchCooperativeKernel((const void*)kcoop,
                                               dim3(256, N_), dim3(256),
                                               args, 0, stream);
    if (le != hipSuccess) coop = false;
  }
  if (!coop) {                          // verified 3-dispatch fallback
    kwin<<<dim3(257, N_), 256, 0, stream>>>(x, xs, A, E, cb, W, a2, biastab, wb,
                                            statsbuf);
    kmain<false><<<dim3(256, N_), 256, 0, stream>>>(
        x, xs, A, E, cb, W, wb, a2, biastab, zb, statsbuf, gamma, beta, out);
    kapply<<<dim3(128, N_), 256, 0, stream>>>(zb, x, statsbuf, gamma, beta, out);
  }
}

// Round 10
// 129.615 us; speedup vs baseline: 1.0057x; 1.0057x over previous
//
#include <hip/hip_runtime.h>
#include <hip/hip_cooperative_groups.h>

namespace cg = cooperative_groups;

// ST-GCN fused block for MI355X (gfx950).  FP32 I/O, bf16 at MFMA boundaries.
// Preferred: ONE cooperative dispatch (1024 blocks = 256 CU x 4):
//   phase A: window-sum (each block: 8 l's x 32 ci, tile aliases T1) + prep
//            distributed over five n==1 blocks -> xs/tables/statsbuf
//   grid.sync (fences publish xs/tables/zeros)
//   phase B: stage1/stage2 MFMA (B-frags direct from xs), z -> regs
//   phase C: zl park (T1 alias) -> stats atomics -> x prefetch -> grid.sync
//            -> per-block 16 KB stats reduce -> BN+ReLU+residual f32x4 out.
// This round: v_cvt_pk_bf16_f32 for all paired f32->bf16 (replaces ~10-instr
// hand-RNE pairs with 1 instr), loop-invariant a2/bias hoisting.
// Fallback: kwin -> kmain<false> -> zb -> kapply (verified 3-dispatch path).
// xs layout: [n][l][25 v][64 ci] bf16.   statsbuf: 32 copies x 128 f32.

typedef unsigned short ushort_t;
typedef __attribute__((ext_vector_type(8))) short short8;   // 8 x bf16 MFMA frag
typedef __attribute__((ext_vector_type(4))) float f32x4;
typedef __attribute__((ext_vector_type(4))) unsigned short us4;

#define N_  4
#define CI_ 64
#define CO_ 64
#define L_  1024
#define V_  25
#define P_  3
#define KS_ 9
#define NLV 102400.0f   // N_*L_*V_  (BN population count per channel)
#define NREP 32         // stats replication factor
#define TSTR 406        // window tile row stride (ushort); u32-friendly

__device__ __forceinline__ float b2f(ushort_t u) {
  union { float f; unsigned int i; } c; c.i = ((unsigned int)u) << 16; return c.f;
}
__device__ __forceinline__ ushort_t f2b(float f) {
  union { float f; unsigned int i; } c; c.f = f;
  unsigned int u = c.i;
  u += 0x7fffu + ((u >> 16) & 1u);      // round-to-nearest-even
  return (ushort_t)(u >> 16);
}
// HW pack: 2 f32 -> u32 of 2 bf16 (RNE), single VALU instruction.
__device__ __forceinline__ unsigned int cvtpk(float lo, float hi) {
  unsigned int r;
  asm("v_cvt_pk_bf16_f32 %0, %1, %2" : "=v"(r) : "v"(lo), "v"(hi));
  return r;
}
__device__ __forceinline__ float lo2f(unsigned int u) {
  union { float f; unsigned int i; } c; c.i = u << 16; return c.f;
}
__device__ __forceinline__ float hi2f(unsigned int u) {
  union { float f; unsigned int i; } c; c.i = u & 0xffff0000u; return c.f;
}

// ---------------------------------------------------------------------------
// kwin (FALLBACK only): window-sum + prep, as verified in R8.
__global__ __launch_bounds__(256) void kwin(
    const float* __restrict__ x, ushort_t* __restrict__ xs,
    const float* __restrict__ A, const float* __restrict__ E,
    const float* __restrict__ cb, const float* __restrict__ W,
    ushort_t* __restrict__ a2raw, float* __restrict__ biastab,
    ushort_t* __restrict__ wb, float* __restrict__ statsbuf)
{
  const int bx = blockIdx.x;                    // 0..256
  const int n = blockIdx.y;
  const int tid = threadIdx.x;

  if (bx == 256) {                              // ---- prep block ----
    if (n != 0) return;
    __shared__ float colA[P_ * 32];
    if (tid < P_ * 32) {
      int p = tid >> 5, w = tid & 31;
      float s = 0.f;
      if (w < V_)
        for (int v = 0; v < V_; ++v) {
          int idx = (p * V_ + v) * V_ + w;
          s += A[idx] * E[idx];
        }
      colA[tid] = s;
    }
    for (int e = tid; e < 32 * 96; e += 256) {
      int w = e / 96, k = e - w * 96;
      int p = k >> 5, v = k & 31;
      float val = 0.f;
      if (w < V_ && v < V_) {
        int idx = (p * V_ + v) * V_ + w;
        val = A[idx] * E[idx];
      }
      a2raw[e] = f2b(val);
    }
    for (int e = tid; e < 192 * 64; e += 256) wb[e] = f2b(W[e]);
    __syncthreads();
    for (int e = tid; e < 32 * 64; e += 256) {
      int w = e >> 6, c = e & 63;
      float s = 0.f;
      for (int p = 0; p < P_; ++p) s += cb[p * 64 + c] * colA[p * 32 + w];
      biastab[e] = s;
    }
    for (int e = tid; e < NREP * 128; e += 256) statsbuf[e] = 0.f;
    return;
  }

  const int chunk = bx >> 1, half = bx & 1;     // 8 l's, 32 ci
  __shared__ __align__(16) ushort_t tile[32 * TSTR];
  const int l0 = chunk * 8;
  const long xn = (long)n * CI_ * L_ * V_ + (long)(half * 32) * (L_ * V_);
  for (int m = tid; m < 3200; m += 256) {
    int ci = m / 100;
    int j4 = (m - ci * 100) * 4;
    f32x4 d;
    if (chunk == 0 && j4 < 200) {
      d = (f32x4){0.f, 0.f, 0.f, 0.f};
    } else {
      d = *(const f32x4*)(x + xn + (long)ci * (L_ * V_) + (l0 - 8) * V_ + j4);
    }
    unsigned int p0 = (unsigned int)f2b(d[0]) | ((unsigned int)f2b(d[1]) << 16);
    unsigned int p1 = (unsigned int)f2b(d[2]) | ((unsigned int)f2b(d[3]) << 16);
    *(unsigned int*)(&tile[ci * TSTR + j4])     = p0;
    *(unsigned int*)(&tile[ci * TSTR + j4 + 2]) = p1;
  }
  __syncthreads();
  const long xsbase = ((long)n * L_ + l0) * 1600 + half * 32;
  for (int cp = tid; cp < 400; cp += 256) {
    const int v = cp >> 4, ci = (cp & 15) * 2;
    const ushort_t* c0 = &tile[ci * TSTR + v];
    const ushort_t* c1 = c0 + TSTR;
    float s0 = 0.f, s1 = 0.f;
#pragma unroll
    for (int li = 0; li < 9; ++li) { s0 += b2f(c0[li * 25]); s1 += b2f(c1[li * 25]); }
    *(unsigned int*)(xs + xsbase + v * 64 + ci) =
        (unsigned int)f2b(s0) | ((unsigned int)f2b(s1) << 16);
#pragma unroll
    for (int l_ = 1; l_ < 8; ++l_) {
      s0 += b2f(c0[(l_ + 8) * 25]) - b2f(c0[(l_ - 1) * 25]);
      s1 += b2f(c1[(l_ + 8) * 25]) - b2f(c1[(l_ - 1) * 25]);
      *(unsigned int*)(xs + xsbase + l_ * 1600 + v * 64 + ci) =
          (unsigned int)f2b(s0) | ((unsigned int)f2b(s1) << 16);
    }
  }
}

// ---------------------------------------------------------------------------
// kmain<COOP>: COOP=true does window phase A + grid.sync + stage1/2 + BN out.
//              COOP=false is the verified fallback (xs from kwin, z -> zb).
template<bool COOP>
__global__ __launch_bounds__(256, 4) void kmain(
    const float*    __restrict__ x,       // [n][ci][l][v] f32
    ushort_t*       __restrict__ xs,      // [n][l][1600] bf16
    const float*    __restrict__ A, const float* __restrict__ E,
    const float*    __restrict__ cb, const float* __restrict__ W,
    ushort_t*       __restrict__ wb,      // [192][64] bf16
    ushort_t*       __restrict__ a2,      // [32 w][96 k] bf16
    float*          __restrict__ biastab, // [32 w][64 c] f32
    ushort_t*       __restrict__ zb,
    float*          __restrict__ statsbuf,
    const float*    __restrict__ gamma,
    const float*    __restrict__ beta,
    float*          __restrict__ out)
{
  const int lb = blockIdx.x;            // 4 l's per block (0..255)
  const int n  = blockIdx.y;
  const int tid = threadIdx.x, lane = tid & 63, wv = tid >> 6;
  const int m16 = lane & 15, quad = lane >> 4;

  __shared__ __align__(16) ushort_t T1[13312];   // [l_][c][104]  26.6 KB
  __shared__ float colA[P_ * 32];                // prep scratch   0.4 KB
  // COOP aliases: phase A tile = T1 (32x406 = 12,992), phase C zl = T1
  // (100x68), part = f32 @ T1[8192], scsh = f32 @ T1[8704].

  if constexpr (COOP) {
    // ================= phase A: window-sum (kwin folded in) ================
    ushort_t* tile = T1;
    const int chunk = lb >> 1, half = lb & 1;   // 8 l's, 32 ci
    const int l0 = chunk * 8;
    const long xn = (long)n * CI_ * L_ * V_ + (long)(half * 32) * (L_ * V_);
    for (int m = tid; m < 3200; m += 256) {
      int ci = m / 100;
      int j4 = (m - ci * 100) * 4;
      f32x4 d;
      if (chunk == 0 && j4 < 200) {
        d = (f32x4){0.f, 0.f, 0.f, 0.f};        // l < 0 halo
      } else {
        d = *(const f32x4*)(x + xn + (long)ci * (L_ * V_) + (l0 - 8) * V_ + j4);
      }
      *(unsigned int*)(&tile[ci * TSTR + j4])     = cvtpk(d[0], d[1]);
      *(unsigned int*)(&tile[ci * TSTR + j4 + 2]) = cvtpk(d[2], d[3]);
    }
    // distributed prep (five n==1 blocks do light extra duty)
    if (n == 1) {
      if (lb == 0) {
        for (int e = tid; e < 32 * 96; e += 256) {
          int w = e / 96, k = e - w * 96;
          int p = k >> 5, v = k & 31;
          float val = 0.f;
          if (w < V_ && v < V_) {
            int idx = (p * V_ + v) * V_ + w;
            val = A[idx] * E[idx];
          }
          a2[e] = f2b(val);
        }
      } else if (lb == 1) {
        for (int e = tid; e < 6144; e += 256) wb[e] = f2b(W[e]);
      } else if (lb == 2) {
        for (int e = tid; e < 6144; e += 256) wb[6144 + e] = f2b(W[6144 + e]);
      } else if (lb == 3) {
        for (int e = tid; e < NREP * 128; e += 256) statsbuf[e] = 0.f;
      } else if (lb == 4) {
        if (tid < P_ * 32) {
          int p = tid >> 5, w = tid & 31;
          float s = 0.f;
          if (w < V_)
            for (int v = 0; v < V_; ++v) {
              int idx = (p * V_ + v) * V_ + w;
              s += A[idx] * E[idx];
            }
          colA[tid] = s;
        }
      }
    }
    __syncthreads();
    const long xsbase = ((long)n * L_ + l0) * 1600 + half * 32;
    for (int cp = tid; cp < 400; cp += 256) {
      const int v = cp >> 4, ci = (cp & 15) * 2;
      const ushort_t* c0 = &tile[ci * TSTR + v];
      const ushort_t* c1 = c0 + TSTR;
      float s0 = 0.f, s1 = 0.f;
#pragma unroll
      for (int li = 0; li < 9; ++li) { s0 += b2f(c0[li * 25]); s1 += b2f(c1[li * 25]); }
      *(unsigned int*)(xs + xsbase + v * 64 + ci) = cvtpk(s0, s1);
#pragma unroll
      for (int l_ = 1; l_ < 8; ++l_) {
        s0 += b2f(c0[(l_ + 8) * 25]) - b2f(c0[(l_ - 1) * 25]);
        s1 += b2f(c1[(l_ + 8) * 25]) - b2f(c1[(l_ - 1) * 25]);
        *(unsigned int*)(xs + xsbase + l_ * 1600 + v * 64 + ci) = cvtpk(s0, s1);
      }
    }
    if (n == 1 && lb == 4) {
      for (int e = tid; e < 32 * 64; e += 256) {
        int w = e >> 6, c = e & 63;
        float s = 0.f;
        for (int p = 0; p < P_; ++p) s += cb[p * 64 + c] * colA[p * 32 + w];
        biastab[e] = s;
      }
    }
    cg::this_grid().sync();             // publish xs / tables / statsbuf zeros
  }

  // ================= phase B: stage1 + stage2 MFMA =======================
  short8 af[3][2];
#pragma unroll
  for (int i = 0; i < 3; ++i) {
    const ushort_t* wrow = wb + ((wv * 3 + i) * 16 + m16) * 64 + quad * 8;
    af[i][0] = *(const short8*)(wrow);
    af[i][1] = *(const short8*)(wrow + 32);
  }

  // loop-invariant hoists: a2 B-frags + bias rows (both pairs use them)
  short8 bfr2[2][3];
#pragma unroll
  for (int nt = 0; nt < 2; ++nt)
#pragma unroll
    for (int ks = 0; ks < 3; ++ks)
      bfr2[nt][ks] = *(const short8*)(a2 + (nt * 16 + m16) * 96 + ks * 32 + quad * 8);

  const int cbase = wv * 16 + quad * 4;
  f32x4 biasv[2];
#pragma unroll
  for (int nt = 0; nt < 2; ++nt)        // w rows 25..31 exist (zero), safe
    biasv[nt] = *(const f32x4*)(biastab + (nt * 16 + m16) * 64 + cbase);

  const ushort_t* xsb = xs + ((long)n * L_ + 4 * lb) * 1600;
  float s1[4] = {0.f, 0.f, 0.f, 0.f}, s2[4] = {0.f, 0.f, 0.f, 0.f};
  unsigned int zpk[2][2][2][2];         // [pair][l_][nt][h]: 2 bf16 per u32

#pragma unroll
  for (int pair = 0; pair < 2; ++pair) {
    // ---- stage 1: B-frags direct from global xs (predicated zero v>=25) ----
    short8 bfr[4][2];
#pragma unroll
    for (int nt = 0; nt < 4; ++nt) {
      const int v = (nt & 1) * 16 + m16;
      const int l_ = pair * 2 + (nt >> 1);
#pragma unroll
      for (int ks = 0; ks < 2; ++ks) {
        short8 t = (short8){0, 0, 0, 0, 0, 0, 0, 0};
        if (v < V_)
          t = *(const short8*)(xsb + l_ * 1600 + v * 64 + ks * 32 + quad * 8);
        bfr[nt][ks] = t;
      }
    }

    f32x4 acc1[3][4];
#pragma unroll
    for (int i = 0; i < 3; ++i)
#pragma unroll
      for (int j = 0; j < 4; ++j) acc1[i][j] = (f32x4){0.f, 0.f, 0.f, 0.f};

#pragma unroll
    for (int i = 0; i < 3; ++i)
#pragma unroll
      for (int nt = 0; nt < 4; ++nt) {
        acc1[i][nt] = __builtin_amdgcn_mfma_f32_16x16x32_bf16(af[i][0], bfr[nt][0], acc1[i][nt], 0, 0, 0);
        acc1[i][nt] = __builtin_amdgcn_mfma_f32_16x16x32_bf16(af[i][1], bfr[nt][1], acc1[i][nt], 0, 0, 0);
      }

    __syncthreads();                    // tile (pair 0) / prior T1 reads done
    // repack t1 -> T1[l_][c][p*32+v]  (D: row = quad*4+r, col = m16)
#pragma unroll
    for (int i = 0; i < 3; ++i) {
      const int mt = wv * 3 + i;
#pragma unroll
      for (int nt = 0; nt < 4; ++nt) {
        const int l_ = nt >> 1;
        const int col = (nt & 1) * 16 + m16;
#pragma unroll
        for (int r = 0; r < 4; ++r) {
          int k = mt * 16 + quad * 4 + r;        // k = p*64 + c
          T1[l_ * 6656 + (k & 63) * 104 + (k >> 6) * 32 + col] = f2b(acc1[i][nt][r]);
        }
      }
    }
    __syncthreads();

    // ---- stage 2: 12 MFMA; T1 A-frags from LDS, a2 frags preloaded ----
    f32x4 acc2[2][2];
#pragma unroll
    for (int l_ = 0; l_ < 2; ++l_)
#pragma unroll
      for (int nt = 0; nt < 2; ++nt) acc2[l_][nt] = (f32x4){0.f, 0.f, 0.f, 0.f};

#pragma unroll
    for (int l_ = 0; l_ < 2; ++l_)
#pragma unroll
      for (int ks = 0; ks < 3; ++ks) {
        short8 afT = *(const short8*)(&T1[l_ * 6656 + (wv * 16 + m16) * 104 + ks * 32 + quad * 8]);
        acc2[l_][0] = __builtin_amdgcn_mfma_f32_16x16x32_bf16(afT, bfr2[0][ks], acc2[l_][0], 0, 0, 0);
        acc2[l_][1] = __builtin_amdgcn_mfma_f32_16x16x32_bf16(afT, bfr2[1][ks], acc2[l_][1], 0, 0, 0);
      }

    // epilogue: + cnt(l)*bias; z -> u32 bf16-pairs (regs) or zb (fallback)
#pragma unroll
    for (int l_ = 0; l_ < 2; ++l_) {
      const int l = 4 * lb + pair * 2 + l_;
      const float cnt = (float)(l + 1 < KS_ ? l + 1 : KS_);
#pragma unroll
      for (int nt = 0; nt < 2; ++nt) {
        const int w = nt * 16 + m16;
        if (w < V_) {
          const f32x4 bias = biasv[nt];
          const unsigned int u01 = cvtpk(acc2[l_][nt][0] + cnt * bias[0],
                                         acc2[l_][nt][1] + cnt * bias[1]);
          const unsigned int u23 = cvtpk(acc2[l_][nt][2] + cnt * bias[2],
                                         acc2[l_][nt][3] + cnt * bias[3]);
          // stats on the stored (bf16-rounded) values
          const float z0 = lo2f(u01), z1 = hi2f(u01);
          const float z2 = lo2f(u23), z3 = hi2f(u23);
          s1[0] += z0; s2[0] += z0 * z0;
          s1[1] += z1; s2[1] += z1 * z1;
          s1[2] += z2; s2[2] += z2 * z2;
          s1[3] += z3; s2[3] += z3 * z3;
          if constexpr (COOP) {
            zpk[pair][l_][nt][0] = u01;
            zpk[pair][l_][nt][1] = u23;
          } else {
            ushort_t* zp = &zb[(((long)(n * L_ + l) * V_ + w) << 6) + cbase];
            *(unsigned int*)(zp)     = u01;
            *(unsigned int*)(zp + 2) = u23;
          }
        }
      }
    }
  }
  // in-quad reduction over m16 (lanes of a quad share channels cbase..cbase+3)
#pragma unroll
  for (int off = 1; off < 16; off <<= 1) {
#pragma unroll
    for (int r = 0; r < 4; ++r) {
      s1[r] += __shfl_xor(s1[r], off, 64);
      s2[r] += __shfl_xor(s2[r], off, 64);
    }
  }
  if (m16 == 0) {
    float* sb = statsbuf + ((n * 256 + lb) & (NREP - 1)) * 128;
#pragma unroll
    for (int r = 0; r < 4; ++r) {
      atomicAdd(&sb[cbase + r], s1[r]);
      atomicAdd(&sb[64 + cbase + r], s2[r]);
    }
  }

  if constexpr (COOP) {
    // ================= phase C: BN finalize + output =======================
    __syncthreads();                    // T1 MFMA reads done; re-alias as zl
    ushort_t* zl = T1;                  // [rr][c^e], 100 x 68
#pragma unroll
    for (int pair = 0; pair < 2; ++pair)
#pragma unroll
      for (int l_ = 0; l_ < 2; ++l_)
#pragma unroll
        for (int nt = 0; nt < 2; ++nt) {
          const int w = nt * 16 + m16;
          if (w < V_) {
            const int rr = (pair * 2 + l_) * 25 + w;
            const int e = ((rr >> 2) & 31) << 1;
            *(unsigned int*)(&zl[rr * 68 + (cbase ^ e)])       = zpk[pair][l_][nt][0];
            *(unsigned int*)(&zl[rr * 68 + ((cbase + 2) ^ e)]) = zpk[pair][l_][nt][1];
          }
        }

    // prefetch phase-3 residual x (hides HBM under sync+reduce)
    const long obase = (long)(n * 64) * (L_ * V_) + lb * 100;
    f32x4 xv[7];
#pragma unroll
    for (int i = 0; i < 7; ++i) {
      const int m = tid + i * 256;
      if (m < 1600) {
        const int c = m / 25, q = m - c * 25;
        xv[i] = *(const f32x4*)(x + obase + (long)c * (L_ * V_) + q * 4);
      }
    }

    cg::this_grid().sync();             // all stats atomics done grid-wide

    // every block reduces the 16 KB statsbuf (L3-hot)
    float* part = (float*)&T1[8192];
    float* scsh = (float*)&T1[8704];
    {
      const int slot = tid & 127, hf = tid >> 7;
      float a = 0.f;
      for (int k = hf; k < NREP; k += 2)
        a += __hip_atomic_load(&statsbuf[k * 128 + slot],
                               __ATOMIC_RELAXED, __HIP_MEMORY_SCOPE_AGENT);
      part[tid] = a;
    }
    __syncthreads();
    if (tid < 64) {
      const float inv = 1.0f / NLV;
      float s    = part[tid]      + part[128 + tid];
      float sq   = part[64 + tid] + part[192 + tid];
      float mean = s * inv;
      float var  = sq * inv - mean * mean;
      float rstd = rsqrtf(var + 1e-5f);
      float g = gamma[tid];
      scsh[tid]      = rstd * g;
      scsh[64 + tid] = beta[tid] - mean * rstd * g;
    }
    __syncthreads();

    // BN + ReLU + residual, coalesced f32x4 out
#pragma unroll
    for (int i = 0; i < 7; ++i) {
      const int m = tid + i * 256;
      if (m < 1600) {
        const int c = m / 25, q = m - c * 25, rr = q * 4;
        const int e = q << 1;           // ((rr>>2)&31)<<1, q<25
        const long xi = obase + (long)c * (L_ * V_) + rr;
        const float scc = scsh[c], shc = scsh[64 + c];
        f32x4 o;
#pragma unroll
        for (int j = 0; j < 4; ++j) {
          float z = b2f(zl[(rr + j) * 68 + (c ^ e)]);
          float y = fmaxf(z * scc + shc, 0.f);
          o[j] = fmaxf(y + xv[i][j], 0.f);
        }
        *(f32x4*)(out + xi) = o;
      }
    }
  }
}

// ---------------------------------------------------------------------------
// kapply (fallback only).
__global__ __launch_bounds__(256) void kapply(
    const ushort_t* __restrict__ zb, const float* __restrict__ x,
    const float* __restrict__ statsbuf,
    const float* __restrict__ gamma, const float* __restrict__ beta,
    float* __restrict__ out)
{
  const int n = blockIdx.y, chunk = blockIdx.x;   // 8 l's per block
  const int tid = threadIdx.x;
  __shared__ __align__(16) ushort_t zl[200 * 66];
  __shared__ f32x4 red[8][32];
  __shared__ float sc[64], sh[64];
  const long zbase = (long)((n * L_ + chunk * 8) * V_) * 64;
  for (int m = tid; m < 6400; m += 256) {
    const int row = m >> 5, c2 = (m & 31) * 2;
    const int cs = c2 ^ (((row >> 2) & 31) << 1);
    *(unsigned int*)(&zl[row * 66 + cs]) = ((const unsigned int*)(zb + zbase))[m];
  }
  {
    const int s4 = tid & 31, grp = tid >> 5;
    const f32x4* sb4 = (const f32x4*)statsbuf;
    f32x4 a = (f32x4){0.f, 0.f, 0.f, 0.f};
    for (int k = grp; k < NREP; k += 8) {
      f32x4 v = sb4[k * 32 + s4];
      a[0] += v[0]; a[1] += v[1]; a[2] += v[2]; a[3] += v[3];
    }
    red[grp][s4] = a;
  }
  __syncthreads();
  if (tid < 64) {
    const float inv = 1.0f / NLV;
    float s = 0.f, sq = 0.f;
#pragma unroll
    for (int g = 0; g < 8; ++g) {
      s  += red[g][tid >> 2][tid & 3];
      sq += red[g][16 + (tid >> 2)][tid & 3];
    }
    float mean = s * inv;
    float var  = sq * inv - mean * mean;
    float rstd = rsqrtf(var + 1e-5f);
    float g = gamma[tid];
    sc[tid] = rstd * g;
    sh[tid] = beta[tid] - mean * rstd * g;
  }
  __syncthreads();
  const long obase = ((long)(n * 64) * L_ + chunk * 8) * V_;
  for (int m = tid; m < 3200; m += 256) {
    int c = m / 50, q = m - c * 50, rr = q * 4;
    const int e = ((q & 31) << 1);
    long xi = obase + (long)c * (L_ * V_) + rr;
    f32x4 xv = *(const f32x4*)(x + xi);
    const float scc = sc[c], shc = sh[c];
    f32x4 o;
#pragma unroll
    for (int j = 0; j < 4; ++j) {
      float z = b2f(zl[(rr + j) * 66 + (c ^ e)]);
      float y = fmaxf(z * scc + shc, 0.f);
      o[j] = fmaxf(y + xv[j], 0.f);
    }
    *(f32x4*)(out + xi) = o;
  }
}

// ---------------------------------------------------------------------------
extern "C" void kernel_launch(void* const* d_in, const int* in_sizes, int n_in,
                              void* d_out, int out_size, void* d_ws, size_t ws_size,
                              hipStream_t stream)
{
  const float* x     = (const float*)d_in[0];
  const float* A     = (const float*)d_in[1];
  const float* E     = (const float*)d_in[2];
  const float* W     = (const float*)d_in[3];
  const float* cb    = (const float*)d_in[4];
  const float* gamma = (const float*)d_in[5];
  const float* beta  = (const float*)d_in[6];
  float* out = (float*)d_out;

  char* ws = (char*)d_ws;
  const size_t XS_OFF   = 0;                       // 13,107,200 B (bf16 xs)
  const size_t ZB_OFF   = 13107200;                // 13,107,200 B (bf16 zb, fallback)
  const size_t WB_OFF   = 26214400;                // 24,576 B (bf16 Wb)
  const size_t A2_OFF   = WB_OFF + 32768;          // 6,144 B
  const size_t BIAS_OFF = A2_OFF + 16384;          // 8,192 B
  const size_t STAT_OFF = BIAS_OFF + 16384;        // 16,384 B (32 x 128 f32)
  ushort_t* xs       = (ushort_t*)(ws + XS_OFF);
  ushort_t* zb       = (ushort_t*)(ws + ZB_OFF);
  ushort_t* wb       = (ushort_t*)(ws + WB_OFF);
  ushort_t* a2       = (ushort_t*)(ws + A2_OFF);
  float*    biastab  = (float*)(ws + BIAS_OFF);
  float*    statsbuf = (float*)(ws + STAT_OFF);

  // validate cooperative residency (host-side query; capture-safe)
  auto kcoop = kmain<true>;
  int maxb = 0;
  hipError_t qe = hipOccupancyMaxActiveBlocksPerMultiprocessor(&maxb, kcoop, 256, 0);
  bool coop = (qe == hipSuccess) && (maxb >= 4);

  if (coop) {
    void* args[] = {(void*)&x, &xs, (void*)&A, (void*)&E, (void*)&cb, (void*)&W,
                    &wb, &a2, &biastab, &zb, &statsbuf,
                    (void*)&gamma, (void*)&beta, &out};
    hipError_t le = hipLaunchCooperativeKernel((const void*)kcoop,
                                               dim3(256, N_), dim3(256),
                                               args, 0, stream);
    if (le != hipSuccess) coop = false;
  }
  if (!coop) {                          // verified 3-dispatch fallback
    kwin<<<dim3(257, N_), 256, 0, stream>>>(x, xs, A, E, cb, W, a2, biastab, wb,
                                            statsbuf);
    kmain<false><<<dim3(256, N_), 256, 0, stream>>>(
        x, xs, A, E, cb, W, wb, a2, biastab, zb, statsbuf, gamma, beta, out);
    kapply<<<dim3(128, N_), 256, 0, stream>>>(zb, x, statsbuf, gamma, beta, out);
  }
}

// Round 11
// 127.301 us; speedup vs baseline: 1.0240x; 1.0182x over previous
//
#include <hip/hip_runtime.h>
#include <hip/hip_cooperative_groups.h>

namespace cg = cooperative_groups;

// ST-GCN fused block for MI355X (gfx950).  FP32 I/O, bf16 at MFMA boundaries.
// Preferred: kprep (8 tiny blocks: tables + statsbuf zero)
//         -> kmain<true> COOPERATIVE, 512 blocks (128 lb x 4 n), 8 l's each:
//   phase A: full 64-ci window in 52 KB tile -> xs (global, block-local L2)
//            __syncthreads only — NO grid sync (block consumes its own xs)
//   phase B: 4 pairs of stage1/stage2 MFMA, z -> regs (32 u32)
//   phase C: zl park (aliases tile) -> stats atomics -> ONE grid.sync ->
//            per-block 16 KB stats reduce -> BN+ReLU+residual f32x4 out.
// Fallback: kwin -> kmain<false> -> zb -> kapply (verified 3-dispatch path).
// xs layout: [n][l][25 v][64 ci] bf16.   statsbuf: 32 copies x 128 f32.

typedef unsigned short ushort_t;
typedef __attribute__((ext_vector_type(8))) short short8;   // 8 x bf16 MFMA frag
typedef __attribute__((ext_vector_type(4))) float f32x4;
typedef __attribute__((ext_vector_type(4))) unsigned short us4;

#define N_  4
#define CI_ 64
#define CO_ 64
#define L_  1024
#define V_  25
#define P_  3
#define KS_ 9
#define NLV 102400.0f   // N_*L_*V_  (BN population count per channel)
#define NREP 32         // stats replication factor
#define TSTR 402        // window tile row stride (ushort); odd-dword, u32-ok

__device__ __forceinline__ float b2f(ushort_t u) {
  union { float f; unsigned int i; } c; c.i = ((unsigned int)u) << 16; return c.f;
}
__device__ __forceinline__ ushort_t f2b(float f) {
  union { float f; unsigned int i; } c; c.f = f;
  unsigned int u = c.i;
  u += 0x7fffu + ((u >> 16) & 1u);      // round-to-nearest-even
  return (ushort_t)(u >> 16);
}
// HW pack: 2 f32 -> u32 of 2 bf16 (RNE), single VALU instruction.
__device__ __forceinline__ unsigned int cvtpk(float lo, float hi) {
  unsigned int r;
  asm("v_cvt_pk_bf16_f32 %0, %1, %2" : "=v"(r) : "v"(lo), "v"(hi));
  return r;
}
__device__ __forceinline__ float lo2f(unsigned int u) {
  union { float f; unsigned int i; } c; c.i = u << 16; return c.f;
}
__device__ __forceinline__ float hi2f(unsigned int u) {
  union { float f; unsigned int i; } c; c.i = u & 0xffff0000u; return c.f;
}

// ---------------------------------------------------------------------------
// kprep: 8 tiny blocks build tables + zero statsbuf (coop path only).
__global__ __launch_bounds__(256) void kprep(
    const float* __restrict__ A, const float* __restrict__ E,
    const float* __restrict__ W, const float* __restrict__ cb,
    ushort_t* __restrict__ a2, float* __restrict__ biastab,
    ushort_t* __restrict__ wb, float* __restrict__ statsbuf)
{
  const int b = blockIdx.x, tid = threadIdx.x;
  if (b == 0) {
    __shared__ float colA[P_ * 32];
    if (tid < P_ * 32) {
      int p = tid >> 5, w = tid & 31;
      float s = 0.f;
      if (w < V_)
        for (int v = 0; v < V_; ++v) {
          int idx = (p * V_ + v) * V_ + w;
          s += A[idx] * E[idx];
        }
      colA[tid] = s;
    }
    __syncthreads();
    for (int e = tid; e < 32 * 64; e += 256) {
      int w = e >> 6, c = e & 63;
      float s = 0.f;
      for (int p = 0; p < P_; ++p) s += cb[p * 64 + c] * colA[p * 32 + w];
      biastab[e] = s;
    }
  } else if (b == 1) {
    for (int e = tid; e < 32 * 96; e += 256) {
      int w = e / 96, k = e - w * 96;
      int p = k >> 5, v = k & 31;
      float val = 0.f;
      if (w < V_ && v < V_) {
        int idx = (p * V_ + v) * V_ + w;
        val = A[idx] * E[idx];
      }
      a2[e] = f2b(val);
    }
  } else if (b < 4) {
    const int base = (b - 2) * 6144;
    for (int e = tid; e < 6144; e += 256) wb[base + e] = f2b(W[base + e]);
  } else {
    const int base = (b - 4) * 1024;    // 4 blocks x 1024 f32 = 32*128
    for (int e = tid; e < 1024; e += 256) statsbuf[base + e] = 0.f;
  }
}

// ---------------------------------------------------------------------------
// kwin (FALLBACK only): window-sum + prep, as verified in R8.
__global__ __launch_bounds__(256) void kwin(
    const float* __restrict__ x, ushort_t* __restrict__ xs,
    const float* __restrict__ A, const float* __restrict__ E,
    const float* __restrict__ cb, const float* __restrict__ W,
    ushort_t* __restrict__ a2raw, float* __restrict__ biastab,
    ushort_t* __restrict__ wb, float* __restrict__ statsbuf)
{
  const int bx = blockIdx.x;                    // 0..256
  const int n = blockIdx.y;
  const int tid = threadIdx.x;

  if (bx == 256) {                              // ---- prep block ----
    if (n != 0) return;
    __shared__ float colA[P_ * 32];
    if (tid < P_ * 32) {
      int p = tid >> 5, w = tid & 31;
      float s = 0.f;
      if (w < V_)
        for (int v = 0; v < V_; ++v) {
          int idx = (p * V_ + v) * V_ + w;
          s += A[idx] * E[idx];
        }
      colA[tid] = s;
    }
    for (int e = tid; e < 32 * 96; e += 256) {
      int w = e / 96, k = e - w * 96;
      int p = k >> 5, v = k & 31;
      float val = 0.f;
      if (w < V_ && v < V_) {
        int idx = (p * V_ + v) * V_ + w;
        val = A[idx] * E[idx];
      }
      a2raw[e] = f2b(val);
    }
    for (int e = tid; e < 192 * 64; e += 256) wb[e] = f2b(W[e]);
    __syncthreads();
    for (int e = tid; e < 32 * 64; e += 256) {
      int w = e >> 6, c = e & 63;
      float s = 0.f;
      for (int p = 0; p < P_; ++p) s += cb[p * 64 + c] * colA[p * 32 + w];
      biastab[e] = s;
    }
    for (int e = tid; e < NREP * 128; e += 256) statsbuf[e] = 0.f;
    return;
  }

  const int chunk = bx >> 1, half = bx & 1;     // 8 l's, 32 ci
  __shared__ __align__(16) ushort_t tile[32 * 406];
  const int l0 = chunk * 8;
  const long xn = (long)n * CI_ * L_ * V_ + (long)(half * 32) * (L_ * V_);
  for (int m = tid; m < 3200; m += 256) {
    int ci = m / 100;
    int j4 = (m - ci * 100) * 4;
    f32x4 d;
    if (chunk == 0 && j4 < 200) {
      d = (f32x4){0.f, 0.f, 0.f, 0.f};
    } else {
      d = *(const f32x4*)(x + xn + (long)ci * (L_ * V_) + (l0 - 8) * V_ + j4);
    }
    *(unsigned int*)(&tile[ci * 406 + j4])     = cvtpk(d[0], d[1]);
    *(unsigned int*)(&tile[ci * 406 + j4 + 2]) = cvtpk(d[2], d[3]);
  }
  __syncthreads();
  const long xsbase = ((long)n * L_ + l0) * 1600 + half * 32;
  for (int cp = tid; cp < 400; cp += 256) {
    const int v = cp >> 4, ci = (cp & 15) * 2;
    const ushort_t* c0 = &tile[ci * 406 + v];
    const ushort_t* c1 = c0 + 406;
    float s0 = 0.f, s1 = 0.f;
#pragma unroll
    for (int li = 0; li < 9; ++li) { s0 += b2f(c0[li * 25]); s1 += b2f(c1[li * 25]); }
    *(unsigned int*)(xs + xsbase + v * 64 + ci) = cvtpk(s0, s1);
#pragma unroll
    for (int l_ = 1; l_ < 8; ++l_) {
      s0 += b2f(c0[(l_ + 8) * 25]) - b2f(c0[(l_ - 1) * 25]);
      s1 += b2f(c1[(l_ + 8) * 25]) - b2f(c1[(l_ - 1) * 25]);
      *(unsigned int*)(xs + xsbase + l_ * 1600 + v * 64 + ci) = cvtpk(s0, s1);
    }
  }
}

// ---------------------------------------------------------------------------
// kmain<COOP>: 8 l's per block (grid 128 x 4).
//   COOP=true : phase A window in-block -> xs (own L2) -> phase B -> phase C.
//   COOP=false: phase B only (xs from kwin), z -> zb; kapply finishes.
template<bool COOP>
__global__ __launch_bounds__(256, 3) void kmain(
    const float*    __restrict__ x,       // [n][ci][l][v] f32
    ushort_t*       __restrict__ xs,      // [n][l][1600] bf16
    const ushort_t* __restrict__ wb,      // [192][64] bf16 (L1-hot)
    const ushort_t* __restrict__ a2,      // [32 w][96 k] bf16 (L1-hot)
    const float*    __restrict__ biastab, // [32 w][64 c] f32 (L1-hot)
    ushort_t*       __restrict__ zb,
    float*          __restrict__ statsbuf,
    const float*    __restrict__ gamma,
    const float*    __restrict__ beta,
    float*          __restrict__ out)
{
  const int lb = blockIdx.x;            // 8 l's per block (0..127)
  const int n  = blockIdx.y;
  const int tid = threadIdx.x, lane = tid & 63, wv = tid >> 6;
  const int m16 = lane & 15, quad = lane >> 4;

  // 51,456 B region; aliased: phase A tile[64][402] -> phase B T1[13312]
  // -> phase C zl[200][68] (27,200 B) + part/scsh above 27,904 B.
  __shared__ __align__(16) ushort_t tile[64 * TSTR];
  ushort_t* T1 = tile;                  // [l_][c][104], 2 l's per pair

  const int l0 = lb * 8;

  if constexpr (COOP) {
    // ================= phase A: window-sum (own 8 l's, 64 ci) =============
    const long xn = (long)n * CI_ * L_ * V_;
    for (int m = tid; m < 6400; m += 256) {     // 64 ci x 100 f32x4
      int ci = m / 100;
      int j4 = (m - ci * 100) * 4;              // 0..396
      f32x4 d;
      if (lb == 0 && j4 < 200) {
        d = (f32x4){0.f, 0.f, 0.f, 0.f};        // l < 0 halo
      } else {
        d = *(const f32x4*)(x + xn + (long)ci * (L_ * V_) + (l0 - 8) * V_ + j4);
      }
      *(unsigned int*)(&tile[ci * TSTR + j4])     = cvtpk(d[0], d[1]);
      *(unsigned int*)(&tile[ci * TSTR + j4 + 2]) = cvtpk(d[2], d[3]);
    }
    __syncthreads();
    const long xsbase = ((long)n * L_ + l0) * 1600;
    for (int cp = tid; cp < 800; cp += 256) {   // (v, ci-pair) columns
      const int v = cp >> 5, ci = (cp & 31) * 2;
      const ushort_t* c0 = &tile[ci * TSTR + v];
      const ushort_t* c1 = c0 + TSTR;
      float s0 = 0.f, s1 = 0.f;
#pragma unroll
      for (int li = 0; li < 9; ++li) { s0 += b2f(c0[li * 25]); s1 += b2f(c1[li * 25]); }
      *(unsigned int*)(xs + xsbase + v * 64 + ci) = cvtpk(s0, s1);
#pragma unroll
      for (int l_ = 1; l_ < 8; ++l_) {
        s0 += b2f(c0[(l_ + 8) * 25]) - b2f(c0[(l_ - 1) * 25]);
        s1 += b2f(c1[(l_ + 8) * 25]) - b2f(c1[(l_ - 1) * 25]);
        *(unsigned int*)(xs + xsbase + l_ * 1600 + v * 64 + ci) = cvtpk(s0, s1);
      }
    }
    __syncthreads();   // xs writes drained (vmcnt 0) + tile dead -> T1 reuse
  }

  // ================= phase B: 4 pairs of stage1 + stage2 ==================
  short8 af[3][2];
#pragma unroll
  for (int i = 0; i < 3; ++i) {
    const ushort_t* wrow = wb + ((wv * 3 + i) * 16 + m16) * 64 + quad * 8;
    af[i][0] = *(const short8*)(wrow);
    af[i][1] = *(const short8*)(wrow + 32);
  }
  short8 bfr2[2][3];
#pragma unroll
  for (int nt = 0; nt < 2; ++nt)
#pragma unroll
    for (int ks = 0; ks < 3; ++ks)
      bfr2[nt][ks] = *(const short8*)(a2 + (nt * 16 + m16) * 96 + ks * 32 + quad * 8);

  const int cbase = wv * 16 + quad * 4;
  f32x4 biasv[2];
#pragma unroll
  for (int nt = 0; nt < 2; ++nt)
    biasv[nt] = *(const f32x4*)(biastab + (nt * 16 + m16) * 64 + cbase);

  const ushort_t* xsb = xs + ((long)n * L_ + l0) * 1600;
  float s1[4] = {0.f, 0.f, 0.f, 0.f}, s2[4] = {0.f, 0.f, 0.f, 0.f};
  unsigned int zpk[4][2][2][2];         // [pair][l_][nt][h]: 2 bf16 per u32

#pragma unroll
  for (int pair = 0; pair < 4; ++pair) {
    // ---- stage 1: B-frags from global xs (block-local L2; v>=25 zero) ----
    short8 bfr[4][2];
#pragma unroll
    for (int nt = 0; nt < 4; ++nt) {
      const int v = (nt & 1) * 16 + m16;
      const int l_ = pair * 2 + (nt >> 1);
#pragma unroll
      for (int ks = 0; ks < 2; ++ks) {
        short8 t = (short8){0, 0, 0, 0, 0, 0, 0, 0};
        if (v < V_)
          t = *(const short8*)(xsb + l_ * 1600 + v * 64 + ks * 32 + quad * 8);
        bfr[nt][ks] = t;
      }
    }

    f32x4 acc1[3][4];
#pragma unroll
    for (int i = 0; i < 3; ++i)
#pragma unroll
      for (int j = 0; j < 4; ++j) acc1[i][j] = (f32x4){0.f, 0.f, 0.f, 0.f};

#pragma unroll
    for (int i = 0; i < 3; ++i)
#pragma unroll
      for (int nt = 0; nt < 4; ++nt) {
        acc1[i][nt] = __builtin_amdgcn_mfma_f32_16x16x32_bf16(af[i][0], bfr[nt][0], acc1[i][nt], 0, 0, 0);
        acc1[i][nt] = __builtin_amdgcn_mfma_f32_16x16x32_bf16(af[i][1], bfr[nt][1], acc1[i][nt], 0, 0, 0);
      }

    if (pair) __syncthreads();          // prior pair's T1 reads complete
    // repack t1 -> T1[l_][c][p*32+v]  (D: row = quad*4+r, col = m16)
#pragma unroll
    for (int i = 0; i < 3; ++i) {
      const int mt = wv * 3 + i;
#pragma unroll
      for (int nt = 0; nt < 4; ++nt) {
        const int l_ = nt >> 1;
        const int col = (nt & 1) * 16 + m16;
#pragma unroll
        for (int r = 0; r < 4; ++r) {
          int k = mt * 16 + quad * 4 + r;        // k = p*64 + c
          T1[l_ * 6656 + (k & 63) * 104 + (k >> 6) * 32 + col] = f2b(acc1[i][nt][r]);
        }
      }
    }
    __syncthreads();

    // ---- stage 2: 12 MFMA; a2 frags preloaded ----
    f32x4 acc2[2][2];
#pragma unroll
    for (int l_ = 0; l_ < 2; ++l_)
#pragma unroll
      for (int nt = 0; nt < 2; ++nt) acc2[l_][nt] = (f32x4){0.f, 0.f, 0.f, 0.f};

#pragma unroll
    for (int l_ = 0; l_ < 2; ++l_)
#pragma unroll
      for (int ks = 0; ks < 3; ++ks) {
        short8 afT = *(const short8*)(&T1[l_ * 6656 + (wv * 16 + m16) * 104 + ks * 32 + quad * 8]);
        acc2[l_][0] = __builtin_amdgcn_mfma_f32_16x16x32_bf16(afT, bfr2[0][ks], acc2[l_][0], 0, 0, 0);
        acc2[l_][1] = __builtin_amdgcn_mfma_f32_16x16x32_bf16(afT, bfr2[1][ks], acc2[l_][1], 0, 0, 0);
      }

    // epilogue: + cnt(l)*bias; z -> u32 bf16-pairs (regs) or zb (fallback)
#pragma unroll
    for (int l_ = 0; l_ < 2; ++l_) {
      const int l = l0 + pair * 2 + l_;
      const float cnt = (float)(l + 1 < KS_ ? l + 1 : KS_);
#pragma unroll
      for (int nt = 0; nt < 2; ++nt) {
        const int w = nt * 16 + m16;
        if (w < V_) {
          const f32x4 bias = biasv[nt];
          const unsigned int u01 = cvtpk(acc2[l_][nt][0] + cnt * bias[0],
                                         acc2[l_][nt][1] + cnt * bias[1]);
          const unsigned int u23 = cvtpk(acc2[l_][nt][2] + cnt * bias[2],
                                         acc2[l_][nt][3] + cnt * bias[3]);
          const float z0 = lo2f(u01), z1 = hi2f(u01);
          const float z2 = lo2f(u23), z3 = hi2f(u23);
          s1[0] += z0; s2[0] += z0 * z0;
          s1[1] += z1; s2[1] += z1 * z1;
          s1[2] += z2; s2[2] += z2 * z2;
          s1[3] += z3; s2[3] += z3 * z3;
          if constexpr (COOP) {
            zpk[pair][l_][nt][0] = u01;
            zpk[pair][l_][nt][1] = u23;
          } else {
            ushort_t* zp = &zb[(((long)(n * L_ + l) * V_ + w) << 6) + cbase];
            *(unsigned int*)(zp)     = u01;
            *(unsigned int*)(zp + 2) = u23;
          }
        }
      }
    }
  }
  // in-quad reduction over m16 (lanes of a quad share channels cbase..cbase+3)
#pragma unroll
  for (int off = 1; off < 16; off <<= 1) {
#pragma unroll
    for (int r = 0; r < 4; ++r) {
      s1[r] += __shfl_xor(s1[r], off, 64);
      s2[r] += __shfl_xor(s2[r], off, 64);
    }
  }
  if (m16 == 0) {
    float* sb = statsbuf + ((n * 128 + lb) & (NREP - 1)) * 128;
#pragma unroll
    for (int r = 0; r < 4; ++r) {
      atomicAdd(&sb[cbase + r], s1[r]);
      atomicAdd(&sb[64 + cbase + r], s2[r]);
    }
  }

  if constexpr (COOP) {
    // ================= phase C: BN finalize + output =======================
    __syncthreads();                    // all T1 reads done; re-alias as zl
    ushort_t* zl = tile;                // [rr][c^e], 200 x 68 (27,200 B)
#pragma unroll
    for (int pair = 0; pair < 4; ++pair)
#pragma unroll
      for (int l_ = 0; l_ < 2; ++l_)
#pragma unroll
        for (int nt = 0; nt < 2; ++nt) {
          const int w = nt * 16 + m16;
          if (w < V_) {
            const int rr = (pair * 2 + l_) * 25 + w;
            const int e = ((rr >> 2) & 31) << 1;
            *(unsigned int*)(&zl[rr * 68 + (cbase ^ e)])       = zpk[pair][l_][nt][0];
            *(unsigned int*)(&zl[rr * 68 + ((cbase + 2) ^ e)]) = zpk[pair][l_][nt][1];
          }
        }

    cg::this_grid().sync();             // all stats atomics done grid-wide

    // every block reduces the 16 KB statsbuf (L3-hot)
    float* part = (float*)&tile[13952]; // bytes 27,904..28,928
    float* scsh = (float*)&tile[14464]; // bytes 28,928..29,440
    {
      const int slot = tid & 127, hf = tid >> 7;
      float a = 0.f;
      for (int k = hf; k < NREP; k += 2)
        a += __hip_atomic_load(&statsbuf[k * 128 + slot],
                               __ATOMIC_RELAXED, __HIP_MEMORY_SCOPE_AGENT);
      part[tid] = a;
    }
    __syncthreads();
    if (tid < 64) {
      const float inv = 1.0f / NLV;
      float s    = part[tid]      + part[128 + tid];
      float sq   = part[64 + tid] + part[192 + tid];
      float mean = s * inv;
      float var  = sq * inv - mean * mean;
      float rstd = rsqrtf(var + 1e-5f);
      float g = gamma[tid];
      scsh[tid]      = rstd * g;
      scsh[64 + tid] = beta[tid] - mean * rstd * g;
    }
    __syncthreads();

    // BN + ReLU + residual, coalesced f32x4 out (8 l's = 3200 f32x4)
    const long obase = (long)(n * 64) * (L_ * V_) + lb * 200;
    for (int m = tid; m < 3200; m += 256) {
      const int c = m / 50, q = m - c * 50, rr = q * 4;
      const int e = (q & 31) << 1;
      const long xi = obase + (long)c * (L_ * V_) + rr;
      const f32x4 xv = *(const f32x4*)(x + xi);
      const float scc = scsh[c], shc = scsh[64 + c];
      f32x4 o;
#pragma unroll
      for (int j = 0; j < 4; ++j) {
        float z = b2f(zl[(rr + j) * 68 + (c ^ e)]);
        float y = fmaxf(z * scc + shc, 0.f);
        o[j] = fmaxf(y + xv[j], 0.f);
      }
      *(f32x4*)(out + xi) = o;
    }
  }
}

// ---------------------------------------------------------------------------
// kapply (fallback only).
__global__ __launch_bounds__(256) void kapply(
    const ushort_t* __restrict__ zb, const float* __restrict__ x,
    const float* __restrict__ statsbuf,
    const float* __restrict__ gamma, const float* __restrict__ beta,
    float* __restrict__ out)
{
  const int n = blockIdx.y, chunk = blockIdx.x;   // 8 l's per block
  const int tid = threadIdx.x;
  __shared__ __align__(16) ushort_t zl[200 * 66];
  __shared__ f32x4 red[8][32];
  __shared__ float sc[64], sh[64];
  const long zbase = (long)((n * L_ + chunk * 8) * V_) * 64;
  for (int m = tid; m < 6400; m += 256) {
    const int row = m >> 5, c2 = (m & 31) * 2;
    const int cs = c2 ^ (((row >> 2) & 31) << 1);
    *(unsigned int*)(&zl[row * 66 + cs]) = ((const unsigned int*)(zb + zbase))[m];
  }
  {
    const int s4 = tid & 31, grp = tid >> 5;
    const f32x4* sb4 = (const f32x4*)statsbuf;
    f32x4 a = (f32x4){0.f, 0.f, 0.f, 0.f};
    for (int k = grp; k < NREP; k += 8) {
      f32x4 v = sb4[k * 32 + s4];
      a[0] += v[0]; a[1] += v[1]; a[2] += v[2]; a[3] += v[3];
    }
    red[grp][s4] = a;
  }
  __syncthreads();
  if (tid < 64) {
    const float inv = 1.0f / NLV;
    float s = 0.f, sq = 0.f;
#pragma unroll
    for (int g = 0; g < 8; ++g) {
      s  += red[g][tid >> 2][tid & 3];
      sq += red[g][16 + (tid >> 2)][tid & 3];
    }
    float mean = s * inv;
    float var  = sq * inv - mean * mean;
    float rstd = rsqrtf(var + 1e-5f);
    float g = gamma[tid];
    sc[tid] = rstd * g;
    sh[tid] = beta[tid] - mean * rstd * g;
  }
  __syncthreads();
  const long obase = ((long)(n * 64) * L_ + chunk * 8) * V_;
  for (int m = tid; m < 3200; m += 256) {
    int c = m / 50, q = m - c * 50, rr = q * 4;
    const int e = ((q & 31) << 1);
    long xi = obase + (long)c * (L_ * V_) + rr;
    f32x4 xv = *(const f32x4*)(x + xi);
    const float scc = sc[c], shc = sh[c];
    f32x4 o;
#pragma unroll
    for (int j = 0; j < 4; ++j) {
      float z = b2f(zl[(rr + j) * 66 + (c ^ e)]);
      float y = fmaxf(z * scc + shc, 0.f);
      o[j] = fmaxf(y + xv[j], 0.f);
    }
    *(f32x4*)(out + xi) = o;
  }
}

// ---------------------------------------------------------------------------
extern "C" void kernel_launch(void* const* d_in, const int* in_sizes, int n_in,
                              void* d_out, int out_size, void* d_ws, size_t ws_size,
                              hipStream_t stream)
{
  const float* x     = (const float*)d_in[0];
  const float* A     = (const float*)d_in[1];
  const float* E     = (const float*)d_in[2];
  const float* W     = (const float*)d_in[3];
  const float* cb    = (const float*)d_in[4];
  const float* gamma = (const float*)d_in[5];
  const float* beta  = (const float*)d_in[6];
  float* out = (float*)d_out;

  char* ws = (char*)d_ws;
  const size_t XS_OFF   = 0;                       // 13,107,200 B (bf16 xs)
  const size_t ZB_OFF   = 13107200;                // 13,107,200 B (bf16 zb, fallback)
  const size_t WB_OFF   = 26214400;                // 24,576 B (bf16 Wb)
  const size_t A2_OFF   = WB_OFF + 32768;          // 6,144 B
  const size_t BIAS_OFF = A2_OFF + 16384;          // 8,192 B
  const size_t STAT_OFF = BIAS_OFF + 16384;        // 16,384 B (32 x 128 f32)
  ushort_t* xs       = (ushort_t*)(ws + XS_OFF);
  ushort_t* zb       = (ushort_t*)(ws + ZB_OFF);
  ushort_t* wb       = (ushort_t*)(ws + WB_OFF);
  ushort_t* a2       = (ushort_t*)(ws + A2_OFF);
  float*    biastab  = (float*)(ws + BIAS_OFF);
  float*    statsbuf = (float*)(ws + STAT_OFF);

  // validate cooperative residency (host-side query; capture-safe)
  auto kcoop = kmain<true>;
  int maxb = 0;
  hipError_t qe = hipOccupancyMaxActiveBlocksPerMultiprocessor(&maxb, kcoop, 256, 0);
  bool coop = (qe == hipSuccess) && (maxb >= 2);   // grid 512 = 256 CU x 2

  if (coop) {
    kprep<<<dim3(8), 256, 0, stream>>>(A, E, W, cb, a2, biastab, wb, statsbuf);
    void* args[] = {(void*)&x, &xs, &wb, &a2, &biastab, &zb, &statsbuf,
                    (void*)&gamma, (void*)&beta, &out};
    hipError_t le = hipLaunchCooperativeKernel((const void*)kcoop,
                                               dim3(128, N_), dim3(256),
                                               args, 0, stream);
    if (le != hipSuccess) coop = false;
  }
  if (!coop) {                          // verified 3-dispatch fallback
    kwin<<<dim3(257, N_), 256, 0, stream>>>(x, xs, A, E, cb, W, a2, biastab, wb,
                                            statsbuf);
    kmain<false><<<dim3(128, N_), 256, 0, stream>>>(
        x, xs, wb, a2, biastab, zb, statsbuf, gamma, beta, out);
    kapply<<<dim3(128, N_), 256, 0, stream>>>(zb, x, statsbuf, gamma, beta, out);
  }
}

// Round 12
// 126.838 us; speedup vs baseline: 1.0278x; 1.0036x over previous
//
#include <hip/hip_runtime.h>
#include <hip/hip_cooperative_groups.h>

namespace cg = cooperative_groups;

// ST-GCN fused block for MI355X (gfx950).  FP32 I/O, bf16 at MFMA boundaries.
// Preferred: kprep (8 tiny blocks: tables + statsbuf zero)
//         -> kmain<true> COOPERATIVE, 512 blocks (128 lb x 4 n), 8 l's each:
//   phase A: full 64-ci window in 52 KB tile -> xsl in LDS (25.6 KB, XOR-
//            swizzled, zero-padded v=25..31) — NO global xs round-trip
//   phase B: 4 pairs of stage1/stage2 MFMA (B-frags from xsl), z -> regs
//   phase C: zl park (aliases tile) -> stats atomics -> ONE grid.sync ->
//            per-block 16 KB stats reduce -> BN+ReLU+residual f32x4 out.
// LDS: tile 51,456 + xsl 25,600 = 77,056 B -> 2 blocks/CU (= grid need).
// Fallback: kwin -> kmain<false> -> zb -> kapply (verified 3-dispatch path).
// statsbuf: 32 copies x 128 f32.

typedef unsigned short ushort_t;
typedef __attribute__((ext_vector_type(8))) short short8;   // 8 x bf16 MFMA frag
typedef __attribute__((ext_vector_type(4))) float f32x4;
typedef __attribute__((ext_vector_type(4))) unsigned short us4;

#define N_  4
#define CI_ 64
#define CO_ 64
#define L_  1024
#define V_  25
#define P_  3
#define KS_ 9
#define NLV 102400.0f   // N_*L_*V_  (BN population count per channel)
#define NREP 32         // stats replication factor
#define TSTR 402        // window tile row stride (ushort)

__device__ __forceinline__ float b2f(ushort_t u) {
  union { float f; unsigned int i; } c; c.i = ((unsigned int)u) << 16; return c.f;
}
__device__ __forceinline__ ushort_t f2b(float f) {
  union { float f; unsigned int i; } c; c.f = f;
  unsigned int u = c.i;
  u += 0x7fffu + ((u >> 16) & 1u);      // round-to-nearest-even
  return (ushort_t)(u >> 16);
}
// HW pack: 2 f32 -> u32 of 2 bf16 (RNE), single VALU instruction.
__device__ __forceinline__ unsigned int cvtpk(float lo, float hi) {
  unsigned int r;
  asm("v_cvt_pk_bf16_f32 %0, %1, %2" : "=v"(r) : "v"(lo), "v"(hi));
  return r;
}
__device__ __forceinline__ float lo2f(unsigned int u) {
  union { float f; unsigned int i; } c; c.i = u << 16; return c.f;
}
__device__ __forceinline__ float hi2f(unsigned int u) {
  union { float f; unsigned int i; } c; c.i = u & 0xffff0000u; return c.f;
}

// ---------------------------------------------------------------------------
// kprep: 8 tiny blocks build tables + zero statsbuf (coop path only).
__global__ __launch_bounds__(256) void kprep(
    const float* __restrict__ A, const float* __restrict__ E,
    const float* __restrict__ W, const float* __restrict__ cb,
    ushort_t* __restrict__ a2, float* __restrict__ biastab,
    ushort_t* __restrict__ wb, float* __restrict__ statsbuf)
{
  const int b = blockIdx.x, tid = threadIdx.x;
  if (b == 0) {
    __shared__ float colA[P_ * 32];
    if (tid < P_ * 32) {
      int p = tid >> 5, w = tid & 31;
      float s = 0.f;
      if (w < V_)
        for (int v = 0; v < V_; ++v) {
          int idx = (p * V_ + v) * V_ + w;
          s += A[idx] * E[idx];
        }
      colA[tid] = s;
    }
    __syncthreads();
    for (int e = tid; e < 32 * 64; e += 256) {
      int w = e >> 6, c = e & 63;
      float s = 0.f;
      for (int p = 0; p < P_; ++p) s += cb[p * 64 + c] * colA[p * 32 + w];
      biastab[e] = s;
    }
  } else if (b == 1) {
    for (int e = tid; e < 32 * 96; e += 256) {
      int w = e / 96, k = e - w * 96;
      int p = k >> 5, v = k & 31;
      float val = 0.f;
      if (w < V_ && v < V_) {
        int idx = (p * V_ + v) * V_ + w;
        val = A[idx] * E[idx];
      }
      a2[e] = f2b(val);
    }
  } else if (b < 4) {
    const int base = (b - 2) * 6144;
    for (int e = tid; e < 6144; e += 256) wb[base + e] = f2b(W[base + e]);
  } else {
    const int base = (b - 4) * 1024;    // 4 blocks x 1024 f32 = 32*128
    for (int e = tid; e < 1024; e += 256) statsbuf[base + e] = 0.f;
  }
}

// ---------------------------------------------------------------------------
// kwin (FALLBACK only): window-sum + prep, as verified in R8.
__global__ __launch_bounds__(256) void kwin(
    const float* __restrict__ x, ushort_t* __restrict__ xs,
    const float* __restrict__ A, const float* __restrict__ E,
    const float* __restrict__ cb, const float* __restrict__ W,
    ushort_t* __restrict__ a2raw, float* __restrict__ biastab,
    ushort_t* __restrict__ wb, float* __restrict__ statsbuf)
{
  const int bx = blockIdx.x;                    // 0..256
  const int n = blockIdx.y;
  const int tid = threadIdx.x;

  if (bx == 256) {                              // ---- prep block ----
    if (n != 0) return;
    __shared__ float colA[P_ * 32];
    if (tid < P_ * 32) {
      int p = tid >> 5, w = tid & 31;
      float s = 0.f;
      if (w < V_)
        for (int v = 0; v < V_; ++v) {
          int idx = (p * V_ + v) * V_ + w;
          s += A[idx] * E[idx];
        }
      colA[tid] = s;
    }
    for (int e = tid; e < 32 * 96; e += 256) {
      int w = e / 96, k = e - w * 96;
      int p = k >> 5, v = k & 31;
      float val = 0.f;
      if (w < V_ && v < V_) {
        int idx = (p * V_ + v) * V_ + w;
        val = A[idx] * E[idx];
      }
      a2raw[e] = f2b(val);
    }
    for (int e = tid; e < 192 * 64; e += 256) wb[e] = f2b(W[e]);
    __syncthreads();
    for (int e = tid; e < 32 * 64; e += 256) {
      int w = e >> 6, c = e & 63;
      float s = 0.f;
      for (int p = 0; p < P_; ++p) s += cb[p * 64 + c] * colA[p * 32 + w];
      biastab[e] = s;
    }
    for (int e = tid; e < NREP * 128; e += 256) statsbuf[e] = 0.f;
    return;
  }

  const int chunk = bx >> 1, half = bx & 1;     // 8 l's, 32 ci
  __shared__ __align__(16) ushort_t tile[32 * 406];
  const int l0 = chunk * 8;
  const long xn = (long)n * CI_ * L_ * V_ + (long)(half * 32) * (L_ * V_);
  for (int m = tid; m < 3200; m += 256) {
    int ci = m / 100;
    int j4 = (m - ci * 100) * 4;
    f32x4 d;
    if (chunk == 0 && j4 < 200) {
      d = (f32x4){0.f, 0.f, 0.f, 0.f};
    } else {
      d = *(const f32x4*)(x + xn + (long)ci * (L_ * V_) + (l0 - 8) * V_ + j4);
    }
    *(unsigned int*)(&tile[ci * 406 + j4])     = cvtpk(d[0], d[1]);
    *(unsigned int*)(&tile[ci * 406 + j4 + 2]) = cvtpk(d[2], d[3]);
  }
  __syncthreads();
  const long xsbase = ((long)n * L_ + l0) * 1600 + half * 32;
  for (int cp = tid; cp < 400; cp += 256) {
    const int v = cp >> 4, ci = (cp & 15) * 2;
    const ushort_t* c0 = &tile[ci * 406 + v];
    const ushort_t* c1 = c0 + 406;
    float s0 = 0.f, s1 = 0.f;
#pragma unroll
    for (int li = 0; li < 9; ++li) { s0 += b2f(c0[li * 25]); s1 += b2f(c1[li * 25]); }
    *(unsigned int*)(xs + xsbase + v * 64 + ci) = cvtpk(s0, s1);
#pragma unroll
    for (int l_ = 1; l_ < 8; ++l_) {
      s0 += b2f(c0[(l_ + 8) * 25]) - b2f(c0[(l_ - 1) * 25]);
      s1 += b2f(c1[(l_ + 8) * 25]) - b2f(c1[(l_ - 1) * 25]);
      *(unsigned int*)(xs + xsbase + l_ * 1600 + v * 64 + ci) = cvtpk(s0, s1);
    }
  }
}

// ---------------------------------------------------------------------------
// kmain<COOP>: 8 l's per block (grid 128 x 4).
//   COOP=true : phase A window -> xsl (LDS, swizzled) -> phase B -> phase C.
//   COOP=false: phase B only (xs from kwin, global), z -> zb; kapply finishes.
template<bool COOP>
__global__ __launch_bounds__(256, 2) void kmain(
    const float*    __restrict__ x,       // [n][ci][l][v] f32
    ushort_t*       __restrict__ xs,      // [n][l][1600] bf16 (fallback only)
    const ushort_t* __restrict__ wb,      // [192][64] bf16 (L1-hot)
    const ushort_t* __restrict__ a2,      // [32 w][96 k] bf16 (L1-hot)
    const float*    __restrict__ biastab, // [32 w][64 c] f32 (L1-hot)
    ushort_t*       __restrict__ zb,
    float*          __restrict__ statsbuf,
    const float*    __restrict__ gamma,
    const float*    __restrict__ beta,
    float*          __restrict__ out)
{
  const int lb = blockIdx.x;            // 8 l's per block (0..127)
  const int n  = blockIdx.y;
  const int tid = threadIdx.x, lane = tid & 63, wv = tid >> 6;
  const int m16 = lane & 15, quad = lane >> 4;

  // smem: tile[64*402]=25,728 us (51,456 B) | xsl[12,800] us (25,600 B).
  // Aliases: T1 = tile[0..13,312); phase C zl = tile[0..13,600),
  // part = f32 @ tile[13,952], scsh = f32 @ tile[14,464].
  __shared__ __align__(16) ushort_t smem[38528];
  ushort_t* tile = smem;
  ushort_t* xsl  = smem + 25728;        // [l][v][64ci], idx ^ ((v&7)<<3)
  ushort_t* T1   = tile;                // [l_][c][104], 2 l's per pair

  const int l0 = lb * 8;

  if constexpr (COOP) {
    // ================= phase A: window-sum (own 8 l's, 64 ci) =============
    const long xn = (long)n * CI_ * L_ * V_;
    for (int m = tid; m < 6400; m += 256) {     // 64 ci x 100 f32x4
      int ci = m / 100;
      int j4 = (m - ci * 100) * 4;              // 0..396
      f32x4 d;
      if (lb == 0 && j4 < 200) {
        d = (f32x4){0.f, 0.f, 0.f, 0.f};        // l < 0 halo
      } else {
        d = *(const f32x4*)(x + xn + (long)ci * (L_ * V_) + (l0 - 8) * V_ + j4);
      }
      *(unsigned int*)(&tile[ci * TSTR + j4])     = cvtpk(d[0], d[1]);
      *(unsigned int*)(&tile[ci * TSTR + j4 + 2]) = cvtpk(d[2], d[3]);
    }
    // zero-pad xsl rows v = 25..31 (so B-frag loads are unpredicated)
    for (int m = tid; m < 1792; m += 256) {     // 8l x 7v x 32 u32
      const int l_ = m / 224, rem = m - l_ * 224;
      const int v = 25 + rem / 32, ci2 = (rem & 31) * 2;
      *(unsigned int*)(&xsl[(l_ * 1600) + ((v * 64 + ci2) ^ ((v & 7) << 3))]) = 0u;
    }
    __syncthreads();
    // sliding window -> xsl (LDS, swizzled); no global xs traffic
    for (int cp = tid; cp < 800; cp += 256) {   // (v, ci-pair) columns
      const int v = cp >> 5, ci = (cp & 31) * 2;
      const int bsw = (v * 64 + ci) ^ ((v & 7) << 3);
      const ushort_t* c0 = &tile[ci * TSTR + v];
      const ushort_t* c1 = c0 + TSTR;
      float s0 = 0.f, s1 = 0.f;
#pragma unroll
      for (int li = 0; li < 9; ++li) { s0 += b2f(c0[li * 25]); s1 += b2f(c1[li * 25]); }
      *(unsigned int*)(&xsl[bsw]) = cvtpk(s0, s1);
#pragma unroll
      for (int l_ = 1; l_ < 8; ++l_) {
        s0 += b2f(c0[(l_ + 8) * 25]) - b2f(c0[(l_ - 1) * 25]);
        s1 += b2f(c1[(l_ + 8) * 25]) - b2f(c1[(l_ - 1) * 25]);
        *(unsigned int*)(&xsl[l_ * 1600 + bsw]) = cvtpk(s0, s1);
      }
    }
    __syncthreads();   // xsl complete; tile dead -> T1 reuse
  }

  // ================= phase B: 4 pairs of stage1 + stage2 ==================
  short8 af[3][2];
#pragma unroll
  for (int i = 0; i < 3; ++i) {
    const ushort_t* wrow = wb + ((wv * 3 + i) * 16 + m16) * 64 + quad * 8;
    af[i][0] = *(const short8*)(wrow);
    af[i][1] = *(const short8*)(wrow + 32);
  }
  short8 bfr2[2][3];
#pragma unroll
  for (int nt = 0; nt < 2; ++nt)
#pragma unroll
    for (int ks = 0; ks < 3; ++ks)
      bfr2[nt][ks] = *(const short8*)(a2 + (nt * 16 + m16) * 96 + ks * 32 + quad * 8);

  const int cbase = wv * 16 + quad * 4;
  f32x4 biasv[2];
#pragma unroll
  for (int nt = 0; nt < 2; ++nt)
    biasv[nt] = *(const f32x4*)(biastab + (nt * 16 + m16) * 64 + cbase);

  const ushort_t* xsb = xs + ((long)n * L_ + l0) * 1600;
  float s1[4] = {0.f, 0.f, 0.f, 0.f}, s2[4] = {0.f, 0.f, 0.f, 0.f};
  unsigned int zpk[4][2][2][2];         // [pair][l_][nt][h]: 2 bf16 per u32

#pragma unroll
  for (int pair = 0; pair < 4; ++pair) {
    // ---- stage 1: B-frags from xsl (COOP, swizzled LDS) or global xs ----
    short8 bfr[4][2];
#pragma unroll
    for (int nt = 0; nt < 4; ++nt) {
      const int v = (nt & 1) * 16 + m16;
      const int l_ = pair * 2 + (nt >> 1);
#pragma unroll
      for (int ks = 0; ks < 2; ++ks) {
        if constexpr (COOP) {
          const int sidx = l_ * 1600 + ((v * 64 + ks * 32 + quad * 8) ^ ((v & 7) << 3));
          bfr[nt][ks] = *(const short8*)(&xsl[sidx]);
        } else {
          short8 t = (short8){0, 0, 0, 0, 0, 0, 0, 0};
          if (v < V_)
            t = *(const short8*)(xsb + l_ * 1600 + v * 64 + ks * 32 + quad * 8);
          bfr[nt][ks] = t;
        }
      }
    }

    f32x4 acc1[3][4];
#pragma unroll
    for (int i = 0; i < 3; ++i)
#pragma unroll
      for (int j = 0; j < 4; ++j) acc1[i][j] = (f32x4){0.f, 0.f, 0.f, 0.f};

#pragma unroll
    for (int i = 0; i < 3; ++i)
#pragma unroll
      for (int nt = 0; nt < 4; ++nt) {
        acc1[i][nt] = __builtin_amdgcn_mfma_f32_16x16x32_bf16(af[i][0], bfr[nt][0], acc1[i][nt], 0, 0, 0);
        acc1[i][nt] = __builtin_amdgcn_mfma_f32_16x16x32_bf16(af[i][1], bfr[nt][1], acc1[i][nt], 0, 0, 0);
      }

    if (pair) __syncthreads();          // prior pair's T1 reads complete
    // repack t1 -> T1[l_][c][p*32+v]  (D: row = quad*4+r, col = m16)
#pragma unroll
    for (int i = 0; i < 3; ++i) {
      const int mt = wv * 3 + i;
#pragma unroll
      for (int nt = 0; nt < 4; ++nt) {
        const int l_ = nt >> 1;
        const int col = (nt & 1) * 16 + m16;
#pragma unroll
        for (int r = 0; r < 4; ++r) {
          int k = mt * 16 + quad * 4 + r;        // k = p*64 + c
          T1[l_ * 6656 + (k & 63) * 104 + (k >> 6) * 32 + col] = f2b(acc1[i][nt][r]);
        }
      }
    }
    __syncthreads();

    // ---- stage 2: 12 MFMA; a2 frags preloaded ----
    f32x4 acc2[2][2];
#pragma unroll
    for (int l_ = 0; l_ < 2; ++l_)
#pragma unroll
      for (int nt = 0; nt < 2; ++nt) acc2[l_][nt] = (f32x4){0.f, 0.f, 0.f, 0.f};

#pragma unroll
    for (int l_ = 0; l_ < 2; ++l_)
#pragma unroll
      for (int ks = 0; ks < 3; ++ks) {
        short8 afT = *(const short8*)(&T1[l_ * 6656 + (wv * 16 + m16) * 104 + ks * 32 + quad * 8]);
        acc2[l_][0] = __builtin_amdgcn_mfma_f32_16x16x32_bf16(afT, bfr2[0][ks], acc2[l_][0], 0, 0, 0);
        acc2[l_][1] = __builtin_amdgcn_mfma_f32_16x16x32_bf16(afT, bfr2[1][ks], acc2[l_][1], 0, 0, 0);
      }

    // epilogue: + cnt(l)*bias; z -> u32 bf16-pairs (regs) or zb (fallback)
#pragma unroll
    for (int l_ = 0; l_ < 2; ++l_) {
      const int l = l0 + pair * 2 + l_;
      const float cnt = (float)(l + 1 < KS_ ? l + 1 : KS_);
#pragma unroll
      for (int nt = 0; nt < 2; ++nt) {
        const int w = nt * 16 + m16;
        if (w < V_) {
          const f32x4 bias = biasv[nt];
          const unsigned int u01 = cvtpk(acc2[l_][nt][0] + cnt * bias[0],
                                         acc2[l_][nt][1] + cnt * bias[1]);
          const unsigned int u23 = cvtpk(acc2[l_][nt][2] + cnt * bias[2],
                                         acc2[l_][nt][3] + cnt * bias[3]);
          const float z0 = lo2f(u01), z1 = hi2f(u01);
          const float z2 = lo2f(u23), z3 = hi2f(u23);
          s1[0] += z0; s2[0] += z0 * z0;
          s1[1] += z1; s2[1] += z1 * z1;
          s1[2] += z2; s2[2] += z2 * z2;
          s1[3] += z3; s2[3] += z3 * z3;
          if constexpr (COOP) {
            zpk[pair][l_][nt][0] = u01;
            zpk[pair][l_][nt][1] = u23;
          } else {
            ushort_t* zp = &zb[(((long)(n * L_ + l) * V_ + w) << 6) + cbase];
            *(unsigned int*)(zp)     = u01;
            *(unsigned int*)(zp + 2) = u23;
          }
        }
      }
    }
  }
  // in-quad reduction over m16 (lanes of a quad share channels cbase..cbase+3)
#pragma unroll
  for (int off = 1; off < 16; off <<= 1) {
#pragma unroll
    for (int r = 0; r < 4; ++r) {
      s1[r] += __shfl_xor(s1[r], off, 64);
      s2[r] += __shfl_xor(s2[r], off, 64);
    }
  }
  if (m16 == 0) {
    float* sb = statsbuf + ((n * 128 + lb) & (NREP - 1)) * 128;
#pragma unroll
    for (int r = 0; r < 4; ++r) {
      atomicAdd(&sb[cbase + r], s1[r]);
      atomicAdd(&sb[64 + cbase + r], s2[r]);
    }
  }

  if constexpr (COOP) {
    // ================= phase C: BN finalize + output =======================
    __syncthreads();                    // all T1 reads done; re-alias as zl
    ushort_t* zl = tile;                // [rr][c^e], 200 x 68 (27,200 B)
#pragma unroll
    for (int pair = 0; pair < 4; ++pair)
#pragma unroll
      for (int l_ = 0; l_ < 2; ++l_)
#pragma unroll
        for (int nt = 0; nt < 2; ++nt) {
          const int w = nt * 16 + m16;
          if (w < V_) {
            const int rr = (pair * 2 + l_) * 25 + w;
            const int e = ((rr >> 2) & 31) << 1;
            *(unsigned int*)(&zl[rr * 68 + (cbase ^ e)])       = zpk[pair][l_][nt][0];
            *(unsigned int*)(&zl[rr * 68 + ((cbase + 2) ^ e)]) = zpk[pair][l_][nt][1];
          }
        }

    cg::this_grid().sync();             // all stats atomics done grid-wide

    // every block reduces the 16 KB statsbuf (L3-hot)
    float* part = (float*)&tile[13952]; // bytes 27,904..28,928
    float* scsh = (float*)&tile[14464]; // bytes 28,928..29,440
    {
      const int slot = tid & 127, hf = tid >> 7;
      float a = 0.f;
      for (int k = hf; k < NREP; k += 2)
        a += __hip_atomic_load(&statsbuf[k * 128 + slot],
                               __ATOMIC_RELAXED, __HIP_MEMORY_SCOPE_AGENT);
      part[tid] = a;
    }
    __syncthreads();
    if (tid < 64) {
      const float inv = 1.0f / NLV;
      float s    = part[tid]      + part[128 + tid];
      float sq   = part[64 + tid] + part[192 + tid];
      float mean = s * inv;
      float var  = sq * inv - mean * mean;
      float rstd = rsqrtf(var + 1e-5f);
      float g = gamma[tid];
      scsh[tid]      = rstd * g;
      scsh[64 + tid] = beta[tid] - mean * rstd * g;
    }
    __syncthreads();

    // BN + ReLU + residual, coalesced f32x4 out (8 l's = 3200 f32x4)
    const long obase = (long)(n * 64) * (L_ * V_) + lb * 200;
    for (int m = tid; m < 3200; m += 256) {
      const int c = m / 50, q = m - c * 50, rr = q * 4;
      const int e = (q & 31) << 1;
      const long xi = obase + (long)c * (L_ * V_) + rr;
      const f32x4 xv = *(const f32x4*)(x + xi);
      const float scc = scsh[c], shc = scsh[64 + c];
      f32x4 o;
#pragma unroll
      for (int j = 0; j < 4; ++j) {
        float z = b2f(zl[(rr + j) * 68 + (c ^ e)]);
        float y = fmaxf(z * scc + shc, 0.f);
        o[j] = fmaxf(y + xv[j], 0.f);
      }
      *(f32x4*)(out + xi) = o;
    }
  }
}

// ---------------------------------------------------------------------------
// kapply (fallback only).
__global__ __launch_bounds__(256) void kapply(
    const ushort_t* __restrict__ zb, const float* __restrict__ x,
    const float* __restrict__ statsbuf,
    const float* __restrict__ gamma, const float* __restrict__ beta,
    float* __restrict__ out)
{
  const int n = blockIdx.y, chunk = blockIdx.x;   // 8 l's per block
  const int tid = threadIdx.x;
  __shared__ __align__(16) ushort_t zl[200 * 66];
  __shared__ f32x4 red[8][32];
  __shared__ float sc[64], sh[64];
  const long zbase = (long)((n * L_ + chunk * 8) * V_) * 64;
  for (int m = tid; m < 6400; m += 256) {
    const int row = m >> 5, c2 = (m & 31) * 2;
    const int cs = c2 ^ (((row >> 2) & 31) << 1);
    *(unsigned int*)(&zl[row * 66 + cs]) = ((const unsigned int*)(zb + zbase))[m];
  }
  {
    const int s4 = tid & 31, grp = tid >> 5;
    const f32x4* sb4 = (const f32x4*)statsbuf;
    f32x4 a = (f32x4){0.f, 0.f, 0.f, 0.f};
    for (int k = grp; k < NREP; k += 8) {
      f32x4 v = sb4[k * 32 + s4];
      a[0] += v[0]; a[1] += v[1]; a[2] += v[2]; a[3] += v[3];
    }
    red[grp][s4] = a;
  }
  __syncthreads();
  if (tid < 64) {
    const float inv = 1.0f / NLV;
    float s = 0.f, sq = 0.f;
#pragma unroll
    for (int g = 0; g < 8; ++g) {
      s  += red[g][tid >> 2][tid & 3];
      sq += red[g][16 + (tid >> 2)][tid & 3];
    }
    float mean = s * inv;
    float var  = sq * inv - mean * mean;
    float rstd = rsqrtf(var + 1e-5f);
    float g = gamma[tid];
    sc[tid] = rstd * g;
    sh[tid] = beta[tid] - mean * rstd * g;
  }
  __syncthreads();
  const long obase = ((long)(n * 64) * L_ + chunk * 8) * V_;
  for (int m = tid; m < 3200; m += 256) {
    int c = m / 50, q = m - c * 50, rr = q * 4;
    const int e = ((q & 31) << 1);
    long xi = obase + (long)c * (L_ * V_) + rr;
    f32x4 xv = *(const f32x4*)(x + xi);
    const float scc = sc[c], shc = sh[c];
    f32x4 o;
#pragma unroll
    for (int j = 0; j < 4; ++j) {
      float z = b2f(zl[(rr + j) * 66 + (c ^ e)]);
      float y = fmaxf(z * scc + shc, 0.f);
      o[j] = fmaxf(y + xv[j], 0.f);
    }
    *(f32x4*)(out + xi) = o;
  }
}

// ---------------------------------------------------------------------------
extern "C" void kernel_launch(void* const* d_in, const int* in_sizes, int n_in,
                              void* d_out, int out_size, void* d_ws, size_t ws_size,
                              hipStream_t stream)
{
  const float* x     = (const float*)d_in[0];
  const float* A     = (const float*)d_in[1];
  const float* E     = (const float*)d_in[2];
  const float* W     = (const float*)d_in[3];
  const float* cb    = (const float*)d_in[4];
  const float* gamma = (const float*)d_in[5];
  const float* beta  = (const float*)d_in[6];
  float* out = (float*)d_out;

  char* ws = (char*)d_ws;
  const size_t XS_OFF   = 0;                       // 13,107,200 B (bf16 xs, fallback)
  const size_t ZB_OFF   = 13107200;                // 13,107,200 B (bf16 zb, fallback)
  const size_t WB_OFF   = 26214400;                // 24,576 B (bf16 Wb)
  const size_t A2_OFF   = WB_OFF + 32768;          // 6,144 B
  const size_t BIAS_OFF = A2_OFF + 16384;          // 8,192 B
  const size_t STAT_OFF = BIAS_OFF + 16384;        // 16,384 B (32 x 128 f32)
  ushort_t* xs       = (ushort_t*)(ws + XS_OFF);
  ushort_t* zb       = (ushort_t*)(ws + ZB_OFF);
  ushort_t* wb       = (ushort_t*)(ws + WB_OFF);
  ushort_t* a2       = (ushort_t*)(ws + A2_OFF);
  float*    biastab  = (float*)(ws + BIAS_OFF);
  float*    statsbuf = (float*)(ws + STAT_OFF);

  // validate cooperative residency (host-side query; capture-safe)
  auto kcoop = kmain<true>;
  int maxb = 0;
  hipError_t qe = hipOccupancyMaxActiveBlocksPerMultiprocessor(&maxb, kcoop, 256, 0);
  bool coop = (qe == hipSuccess) && (maxb >= 2);   // grid 512 = 256 CU x 2

  if (coop) {
    kprep<<<dim3(8), 256, 0, stream>>>(A, E, W, cb, a2, biastab, wb, statsbuf);
    void* args[] = {(void*)&x, &xs, &wb, &a2, &biastab, &zb, &statsbuf,
                    (void*)&gamma, (void*)&beta, &out};
    hipError_t le = hipLaunchCooperativeKernel((const void*)kcoop,
                                               dim3(128, N_), dim3(256),
                                               args, 0, stream);
    if (le != hipSuccess) coop = false;
  }
  if (!coop) {                          // verified 3-dispatch fallback
    kwin<<<dim3(257, N_), 256, 0, stream>>>(x, xs, A, E, cb, W, a2, biastab, wb,
                                            statsbuf);
    kmain<false><<<dim3(128, N_), 256, 0, stream>>>(
        x, xs, wb, a2, biastab, zb, statsbuf, gamma, beta, out);
    kapply<<<dim3(128, N_), 256, 0, stream>>>(zb, x, statsbuf, gamma, beta, out);
  }
}